// Round 1
// baseline (1058.675 us; speedup 1.0000x reference)
//
#include <hip/hip_runtime.h>

#define NEG_SLOPE 0.2f

__device__ __forceinline__ unsigned enc_f(float f) {
  unsigned u = __float_as_uint(f);
  return (u & 0x80000000u) ? ~u : (u | 0x80000000u);
}
__device__ __forceinline__ float dec_f(unsigned u) {
  u = (u & 0x80000000u) ? (u & 0x7FFFFFFFu) : ~u;
  return __uint_as_float(u);
}

// ---------------------------------------------------------------------------
// C[M x 128] = A[M x K] * B[K x 128], fp32, K multiple of 32.
// block = 256 threads; tile 64 rows x 128 cols; each thread 4 rows x 8 cols.
// Safe for in-place C==A when C has 128 cols and A rows are only read by the
// block that writes them (stores happen after the full K loop).
// ---------------------------------------------------------------------------
__global__ __launch_bounds__(256) void gemm_nk128(
    const float* __restrict__ A, const float* __restrict__ B,
    float* __restrict__ C, int M, int K) {
  __shared__ float As[32][64];
  __shared__ float Bs[32][128];
  const int tid = threadIdx.x;
  const int tr = tid >> 4;   // 0..15 -> rows tr*4..tr*4+3
  const int tc = tid & 15;   // 0..15 -> cols tc*4.. and 64+tc*4..
  const int row0 = blockIdx.x * 64;

  float acc[4][8];
#pragma unroll
  for (int r = 0; r < 4; ++r)
#pragma unroll
    for (int c = 0; c < 8; ++c) acc[r][c] = 0.f;

  for (int k0 = 0; k0 < K; k0 += 32) {
    // A tile 64x32 -> As[k][row] (transposed)
#pragma unroll
    for (int j = 0; j < 2; ++j) {
      int s = tid + j * 256;
      int row = s >> 3;
      int kq = (s & 7) << 2;
      int gr = row0 + row;
      float4 v = make_float4(0.f, 0.f, 0.f, 0.f);
      if (gr < M) v = *(const float4*)&A[(size_t)gr * K + k0 + kq];
      As[kq + 0][row] = v.x;
      As[kq + 1][row] = v.y;
      As[kq + 2][row] = v.z;
      As[kq + 3][row] = v.w;
    }
    // B tile 32x128
#pragma unroll
    for (int j = 0; j < 4; ++j) {
      int s = tid + j * 256;
      int kr = s >> 5;
      int cq = (s & 31) << 2;
      *(float4*)&Bs[kr][cq] = *(const float4*)&B[(size_t)(k0 + kr) * 128 + cq];
    }
    __syncthreads();
#pragma unroll
    for (int kk = 0; kk < 32; ++kk) {
      float4 a4 = *(const float4*)&As[kk][tr << 2];
      float4 bA = *(const float4*)&Bs[kk][tc << 2];
      float4 bB = *(const float4*)&Bs[kk][64 + (tc << 2)];
      float av[4] = {a4.x, a4.y, a4.z, a4.w};
      float bv[8] = {bA.x, bA.y, bA.z, bA.w, bB.x, bB.y, bB.z, bB.w};
#pragma unroll
      for (int r = 0; r < 4; ++r)
#pragma unroll
        for (int c = 0; c < 8; ++c) acc[r][c] = fmaf(av[r], bv[c], acc[r][c]);
    }
    __syncthreads();
  }
#pragma unroll
  for (int r = 0; r < 4; ++r) {
    int gr = row0 + (tr << 2) + r;
    if (gr < M) {
      float4 o0 = make_float4(acc[r][0], acc[r][1], acc[r][2], acc[r][3]);
      float4 o1 = make_float4(acc[r][4], acc[r][5], acc[r][6], acc[r][7]);
      *(float4*)&C[(size_t)gr * 128 + (tc << 2)] = o0;
      *(float4*)&C[(size_t)gr * 128 + 64 + (tc << 2)] = o1;
    }
  }
}

// ---------------------------------------------------------------------------
// Per-node attention-score prep: s_src[n][h] = sum_f P[n][h][f]*a_src[h][f]
// One wave per node; lane holds float2 at k = 2*lane of the 128-vector.
// head = lane>>5 (k<64 -> h0, k>=64 -> h1).
// ---------------------------------------------------------------------------
__global__ __launch_bounds__(256) void node_scores(
    const float* __restrict__ P, const float* __restrict__ a_src,
    const float* __restrict__ a_trg, float* __restrict__ ssrc,
    float* __restrict__ strg, int Nn) {
  int wid = (int)((blockIdx.x * blockDim.x + threadIdx.x) >> 6);
  int lane = threadIdx.x & 63;
  if (wid >= Nn) return;
  float2 p = *(const float2*)&P[(size_t)wid * 128 + lane * 2];
  float2 as = *(const float2*)&a_src[lane * 2];
  float2 at = *(const float2*)&a_trg[lane * 2];
  float vs = p.x * as.x + p.y * as.y;
  float vt = p.x * at.x + p.y * at.y;
#pragma unroll
  for (int m = 1; m < 32; m <<= 1) {
    vs += __shfl_xor(vs, m, 64);
    vt += __shfl_xor(vt, m, 64);
  }
  if (lane == 0) {
    ssrc[wid * 2 + 0] = vs;
    strg[wid * 2 + 0] = vt;
  }
  if (lane == 32) {
    ssrc[wid * 2 + 1] = vs;
    strg[wid * 2 + 1] = vt;
  }
}

__global__ __launch_bounds__(256) void deg_count(const int* __restrict__ trg,
                                                 int* __restrict__ deg, int E) {
  int e = blockIdx.x * blockDim.x + threadIdx.x;
  if (e < E) atomicAdd(&deg[trg[e]], 1);
}

// Single-block exclusive scan of degrees -> rowptr + cursor copy.
__global__ __launch_bounds__(256) void scan_deg(const int* __restrict__ deg,
                                                int* __restrict__ rowptr,
                                                int* __restrict__ cursor,
                                                int Nn, int E) {
  __shared__ int partial[256];
  int tid = threadIdx.x;
  int chunk = (Nn + 255) / 256;
  int lo = tid * chunk;
  int hi = lo + chunk;
  if (hi > Nn) hi = Nn;
  int s = 0;
  for (int i = lo; i < hi; ++i) s += deg[i];
  partial[tid] = s;
  __syncthreads();
  if (tid == 0) {
    int run = 0;
    for (int i = 0; i < 256; ++i) {
      int v = partial[i];
      partial[i] = run;
      run += v;
    }
  }
  __syncthreads();
  int run = partial[tid];
  for (int i = lo; i < hi; ++i) {
    rowptr[i] = run;
    cursor[i] = run;
    run += deg[i];
  }
  if (tid == 0) rowptr[Nn] = E;
}

__global__ __launch_bounds__(256) void fill_csr(const int* __restrict__ src,
                                                const int* __restrict__ trg,
                                                int* __restrict__ cursor,
                                                int* __restrict__ SS,
                                                int* __restrict__ SE, int E) {
  int e = blockIdx.x * blockDim.x + threadIdx.x;
  if (e < E) {
    int t = trg[e];
    int p = atomicAdd(&cursor[t], 1);
    SS[p] = src[e];
    SE[p] = e;
  }
}

__global__ __launch_bounds__(256) void edge_scores(
    const int* __restrict__ src, const int* __restrict__ trg,
    const float* __restrict__ ssrc, const float* __restrict__ strg,
    float2* __restrict__ EX, unsigned* __restrict__ gmax, int E) {
  int e = blockIdx.x * blockDim.x + threadIdx.x;
  float m = -3.0e38f;
  if (e < E) {
    int s = src[e];
    int t = trg[e];
    float2 vs = ((const float2*)ssrc)[s];
    float2 vt = ((const float2*)strg)[t];
    float z0 = vs.x + vt.x;
    float z1 = vs.y + vt.y;
    float2 sc;
    sc.x = (z0 >= 0.f) ? z0 : NEG_SLOPE * z0;
    sc.y = (z1 >= 0.f) ? z1 : NEG_SLOPE * z1;
    EX[e] = sc;
    m = fmaxf(sc.x, sc.y);
  }
#pragma unroll
  for (int w = 1; w < 64; w <<= 1) m = fmaxf(m, __shfl_xor(m, w, 64));
  if ((threadIdx.x & 63) == 0) atomicMax(gmax, enc_f(m));
}

__global__ __launch_bounds__(256) void exp_denom(
    const int* __restrict__ trg, float2* __restrict__ EX,
    const unsigned* __restrict__ gmax, float* __restrict__ denom, int E) {
  int e = blockIdx.x * blockDim.x + threadIdx.x;
  if (e >= E) return;
  float M = dec_f(*gmax);
  float2 sc = EX[e];
  float2 ex;
  ex.x = expf(sc.x - M);
  ex.y = expf(sc.y - M);
  EX[e] = ex;
  int t = trg[e];
  atomicAdd(&denom[2 * t + 0], ex.x);
  atomicAdd(&denom[2 * t + 1], ex.y);
}

// ---------------------------------------------------------------------------
// Aggregation: one wave per node. lane holds float2 at k=2*lane of 128-vec.
// LAYER==1: out = max(agg + skip + b, 0) -> (N,128)  [relu(elu(z)) == relu(z)]
// LAYER==2: out = 0.5*(z_h0 + z_h1) + b  -> (N,64)
// ---------------------------------------------------------------------------
template <int LAYER>
__global__ __launch_bounds__(256) void aggregate(
    const int* __restrict__ rowptr, const int* __restrict__ SS,
    const int* __restrict__ SE, const float2* __restrict__ EX,
    const float* __restrict__ denom, const float* __restrict__ P,
    const float* __restrict__ S, const float* __restrict__ bias,
    float* __restrict__ Out, int Nn) {
  int wid = (int)((blockIdx.x * blockDim.x + threadIdx.x) >> 6);
  int lane = threadIdx.x & 63;
  if (wid >= Nn) return;
  int n = wid;
  bool hi = lane >= 32;
  float dh = denom[2 * n + (hi ? 1 : 0)] + 1e-16f;
  float inv = 1.0f / dh;
  int beg = rowptr[n];
  int end = rowptr[n + 1];
  float accx = 0.f, accy = 0.f;
  for (int i = beg; i < end; ++i) {
    int s = SS[i];
    int eid = SE[i];
    float2 exv = EX[eid];
    float att = (hi ? exv.y : exv.x) * inv;
    float2 v = *(const float2*)&P[(size_t)s * 128 + lane * 2];
    accx = fmaf(v.x, att, accx);
    accy = fmaf(v.y, att, accy);
  }
  float2 sk = *(const float2*)&S[(size_t)n * 128 + lane * 2];
  if (LAYER == 1) {
    float2 b = *(const float2*)&bias[lane * 2];
    float zx = fmaxf(accx + sk.x + b.x, 0.f);
    float zy = fmaxf(accy + sk.y + b.y, 0.f);
    float2 o = make_float2(zx, zy);
    *(float2*)&Out[(size_t)n * 128 + lane * 2] = o;
  } else {
    float zx = accx + sk.x;
    float zy = accy + sk.y;
    float ox = __shfl(zx, lane + 32, 64);
    float oy = __shfl(zy, lane + 32, 64);
    if (lane < 32) {
      float2 b = *(const float2*)&bias[lane * 2];
      float rx = 0.5f * (zx + ox) + b.x;
      float ry = 0.5f * (zy + oy) + b.y;
      float2 o = make_float2(rx, ry);
      *(float2*)&Out[(size_t)n * 64 + lane * 2] = o;
    }
  }
}

// ---------------------------------------------------------------------------
extern "C" void kernel_launch(void* const* d_in, const int* in_sizes, int n_in,
                              void* d_out, int out_size, void* d_ws,
                              size_t ws_size, hipStream_t stream) {
  const float* x = (const float*)d_in[0];
  const int* ei = (const int*)d_in[1];
  const float* W0 = (const float*)d_in[2];
  const float* a_src0 = (const float*)d_in[3];
  const float* a_trg0 = (const float*)d_in[4];
  const float* Wsk0 = (const float*)d_in[5];
  const float* b0 = (const float*)d_in[6];
  const float* W2 = (const float*)d_in[7];
  const float* a_src2 = (const float*)d_in[8];
  const float* a_trg2 = (const float*)d_in[9];
  const float* Wsk2 = (const float*)d_in[10];
  const float* b2 = (const float*)d_in[11];

  const int FIN = 256;
  const int N = in_sizes[0] / FIN;
  const int E = in_sizes[1] / 2;
  const int* src = ei;
  const int* trg = ei + E;

  char* base = (char*)d_ws;
  size_t off = 0;
  auto alloc = [&](size_t bytes) -> void* {
    void* p = base + off;
    off += (bytes + 255) & ~(size_t)255;
    return p;
  };
  float* P = (float*)alloc((size_t)N * 128 * sizeof(float));
  float* S = (float*)alloc((size_t)N * 128 * sizeof(float));
  float2* EX = (float2*)alloc((size_t)E * sizeof(float2));
  int* SS = (int*)alloc((size_t)E * sizeof(int));
  int* SE = (int*)alloc((size_t)E * sizeof(int));
  float* ssrc = (float*)alloc((size_t)N * 2 * sizeof(float));
  float* strg = (float*)alloc((size_t)N * 2 * sizeof(float));
  int* rowptr = (int*)alloc((size_t)(N + 1) * sizeof(int));
  int* cursor = (int*)alloc((size_t)N * sizeof(int));
  size_t zbytes = (size_t)N * 4 + (size_t)N * 16 + 8;
  char* zbase = (char*)alloc(zbytes);
  int* deg = (int*)zbase;
  float* denom1 = (float*)(zbase + (size_t)N * 4);
  float* denom2 = denom1 + (size_t)N * 2;
  unsigned* gmax1 = (unsigned*)(denom2 + (size_t)N * 2);
  unsigned* gmax2 = gmax1 + 1;

  hipMemsetAsync(zbase, 0, zbytes, stream);

  dim3 blk(256);
  int gemmBlocks = (N + 63) / 64;
  int edgeBlocks = (E + 255) / 256;
  int nodeBlocks = (N + 3) / 4;

  // ---- layer 1 ----
  gemm_nk128<<<gemmBlocks, blk, 0, stream>>>(x, W0, P, N, FIN);
  gemm_nk128<<<gemmBlocks, blk, 0, stream>>>(x, Wsk0, S, N, FIN);
  node_scores<<<nodeBlocks, blk, 0, stream>>>(P, a_src0, a_trg0, ssrc, strg, N);
  deg_count<<<edgeBlocks, blk, 0, stream>>>(trg, deg, E);
  scan_deg<<<1, blk, 0, stream>>>(deg, rowptr, cursor, N, E);
  fill_csr<<<edgeBlocks, blk, 0, stream>>>(src, trg, cursor, SS, SE, E);
  edge_scores<<<edgeBlocks, blk, 0, stream>>>(src, trg, ssrc, strg, EX, gmax1, E);
  exp_denom<<<edgeBlocks, blk, 0, stream>>>(trg, EX, gmax1, denom1, E);
  aggregate<1><<<nodeBlocks, blk, 0, stream>>>(rowptr, SS, SE, EX, denom1, P, S,
                                               b0, S, N);
  // ---- layer 2 (h lives in S) ----
  gemm_nk128<<<gemmBlocks, blk, 0, stream>>>(S, W2, P, N, 128);
  gemm_nk128<<<gemmBlocks, blk, 0, stream>>>(S, Wsk2, S, N, 128);  // in place
  node_scores<<<nodeBlocks, blk, 0, stream>>>(P, a_src2, a_trg2, ssrc, strg, N);
  edge_scores<<<edgeBlocks, blk, 0, stream>>>(src, trg, ssrc, strg, EX, gmax2, E);
  exp_denom<<<edgeBlocks, blk, 0, stream>>>(trg, EX, gmax2, denom2, E);
  aggregate<2><<<nodeBlocks, blk, 0, stream>>>(rowptr, SS, SE, EX, denom2, P, S,
                                               b2, (float*)d_out, N);
}

// Round 2
// 732.168 us; speedup vs baseline: 1.4459x; 1.4459x over previous
//
#include <hip/hip_runtime.h>

#define NEG_SLOPE 0.2f

// ---------------------------------------------------------------------------
// C[M x 128] = A[M x K] * B[K x 128], fp32, K multiple of 32.
// block = 256 threads; tile 64 rows x 128 cols; each thread 4 rows x 8 cols.
// Safe for in-place C==A when C has 128 cols and A rows are only read by the
// block that writes them (stores happen after the full K loop).
// ---------------------------------------------------------------------------
__global__ __launch_bounds__(256) void gemm_nk128(
    const float* __restrict__ A, const float* __restrict__ B,
    float* __restrict__ C, int M, int K) {
  __shared__ float As[32][64];
  __shared__ float Bs[32][128];
  const int tid = threadIdx.x;
  const int tr = tid >> 4;   // 0..15 -> rows tr*4..tr*4+3
  const int tc = tid & 15;   // 0..15 -> cols tc*4.. and 64+tc*4..
  const int row0 = blockIdx.x * 64;

  float acc[4][8];
#pragma unroll
  for (int r = 0; r < 4; ++r)
#pragma unroll
    for (int c = 0; c < 8; ++c) acc[r][c] = 0.f;

  for (int k0 = 0; k0 < K; k0 += 32) {
    // A tile 64x32 -> As[k][row] (transposed)
#pragma unroll
    for (int j = 0; j < 2; ++j) {
      int s = tid + j * 256;
      int row = s >> 3;
      int kq = (s & 7) << 2;
      int gr = row0 + row;
      float4 v = make_float4(0.f, 0.f, 0.f, 0.f);
      if (gr < M) v = *(const float4*)&A[(size_t)gr * K + k0 + kq];
      As[kq + 0][row] = v.x;
      As[kq + 1][row] = v.y;
      As[kq + 2][row] = v.z;
      As[kq + 3][row] = v.w;
    }
    // B tile 32x128
#pragma unroll
    for (int j = 0; j < 4; ++j) {
      int s = tid + j * 256;
      int kr = s >> 5;
      int cq = (s & 31) << 2;
      *(float4*)&Bs[kr][cq] = *(const float4*)&B[(size_t)(k0 + kr) * 128 + cq];
    }
    __syncthreads();
#pragma unroll
    for (int kk = 0; kk < 32; ++kk) {
      float4 a4 = *(const float4*)&As[kk][tr << 2];
      float4 bA = *(const float4*)&Bs[kk][tc << 2];
      float4 bB = *(const float4*)&Bs[kk][64 + (tc << 2)];
      float av[4] = {a4.x, a4.y, a4.z, a4.w};
      float bv[8] = {bA.x, bA.y, bA.z, bA.w, bB.x, bB.y, bB.z, bB.w};
#pragma unroll
      for (int r = 0; r < 4; ++r)
#pragma unroll
        for (int c = 0; c < 8; ++c) acc[r][c] = fmaf(av[r], bv[c], acc[r][c]);
    }
    __syncthreads();
  }
#pragma unroll
  for (int r = 0; r < 4; ++r) {
    int gr = row0 + (tr << 2) + r;
    if (gr < M) {
      float4 o0 = make_float4(acc[r][0], acc[r][1], acc[r][2], acc[r][3]);
      float4 o1 = make_float4(acc[r][4], acc[r][5], acc[r][6], acc[r][7]);
      *(float4*)&C[(size_t)gr * 128 + (tc << 2)] = o0;
      *(float4*)&C[(size_t)gr * 128 + 64 + (tc << 2)] = o1;
    }
  }
}

// ---------------------------------------------------------------------------
// Per-node attention-score prep: s_src[n][h] = sum_f P[n][h][f]*a_src[h][f]
// One wave per node; lane holds float2 at k = 2*lane of the 128-vector.
// head = lane>>5 (k<64 -> h0, k>=64 -> h1).
// ---------------------------------------------------------------------------
__global__ __launch_bounds__(256) void node_scores(
    const float* __restrict__ P, const float* __restrict__ a_src,
    const float* __restrict__ a_trg, float* __restrict__ ssrc,
    float* __restrict__ strg, int Nn) {
  int wid = (int)((blockIdx.x * blockDim.x + threadIdx.x) >> 6);
  int lane = threadIdx.x & 63;
  if (wid >= Nn) return;
  float2 p = *(const float2*)&P[(size_t)wid * 128 + lane * 2];
  float2 as = *(const float2*)&a_src[lane * 2];
  float2 at = *(const float2*)&a_trg[lane * 2];
  float vs = p.x * as.x + p.y * as.y;
  float vt = p.x * at.x + p.y * at.y;
#pragma unroll
  for (int m = 1; m < 32; m <<= 1) {
    vs += __shfl_xor(vs, m, 64);
    vt += __shfl_xor(vt, m, 64);
  }
  if (lane == 0) {
    ssrc[wid * 2 + 0] = vs;
    strg[wid * 2 + 0] = vt;
  }
  if (lane == 32) {
    ssrc[wid * 2 + 1] = vs;
    strg[wid * 2 + 1] = vt;
  }
}

__global__ __launch_bounds__(256) void deg_count(const int* __restrict__ trg,
                                                 int* __restrict__ deg, int E) {
  int e = blockIdx.x * blockDim.x + threadIdx.x;
  if (e < E) atomicAdd(&deg[trg[e]], 1);
}

// Single-block exclusive scan of degrees -> rowptr + cursor copy.
__global__ __launch_bounds__(256) void scan_deg(const int* __restrict__ deg,
                                                int* __restrict__ rowptr,
                                                int* __restrict__ cursor,
                                                int Nn, int E) {
  __shared__ int partial[256];
  int tid = threadIdx.x;
  int chunk = (Nn + 255) / 256;
  int lo = tid * chunk;
  int hi = lo + chunk;
  if (hi > Nn) hi = Nn;
  int s = 0;
  for (int i = lo; i < hi; ++i) s += deg[i];
  partial[tid] = s;
  __syncthreads();
  if (tid == 0) {
    int run = 0;
    for (int i = 0; i < 256; ++i) {
      int v = partial[i];
      partial[i] = run;
      run += v;
    }
  }
  __syncthreads();
  int run = partial[tid];
  for (int i = lo; i < hi; ++i) {
    rowptr[i] = run;
    cursor[i] = run;
    run += deg[i];
  }
  if (tid == 0) rowptr[Nn] = E;
}

// ---------------------------------------------------------------------------
// Layer-1 fused edge pass: score -> leaky_relu -> exp (no max shift; it
// cancels exactly in exp/sum-exp) -> CSR fill (SS + exp in CSR order) ->
// denom atomics. Records SLOT[e] so layer 2 can reuse the CSR structure.
// ---------------------------------------------------------------------------
__global__ __launch_bounds__(256) void edge_fuse1(
    const int* __restrict__ src, const int* __restrict__ trg,
    const float2* __restrict__ ssrc, const float2* __restrict__ strg,
    int* __restrict__ cursor, int* __restrict__ SS, int* __restrict__ SLOT,
    float2* __restrict__ EXC, float* __restrict__ denom, int E) {
  int e = blockIdx.x * blockDim.x + threadIdx.x;
  if (e >= E) return;
  int s = src[e];
  int t = trg[e];
  float2 vs = ssrc[s];
  float2 vt = strg[t];
  float z0 = vs.x + vt.x;
  float z1 = vs.y + vt.y;
  z0 = (z0 >= 0.f) ? z0 : NEG_SLOPE * z0;
  z1 = (z1 >= 0.f) ? z1 : NEG_SLOPE * z1;
  float e0 = __expf(z0);
  float e1 = __expf(z1);
  int p = atomicAdd(&cursor[t], 1);
  SS[p] = s;
  SLOT[e] = p;
  EXC[p] = make_float2(e0, e1);
  atomicAdd(&denom[2 * t + 0], e0);
  atomicAdd(&denom[2 * t + 1], e1);
}

// Layer-2 fused edge pass: reuses CSR slots from layer 1.
__global__ __launch_bounds__(256) void edge_fuse2(
    const int* __restrict__ src, const int* __restrict__ trg,
    const float2* __restrict__ ssrc, const float2* __restrict__ strg,
    const int* __restrict__ SLOT, float2* __restrict__ EXC,
    float* __restrict__ denom, int E) {
  int e = blockIdx.x * blockDim.x + threadIdx.x;
  if (e >= E) return;
  int s = src[e];
  int t = trg[e];
  float2 vs = ssrc[s];
  float2 vt = strg[t];
  float z0 = vs.x + vt.x;
  float z1 = vs.y + vt.y;
  z0 = (z0 >= 0.f) ? z0 : NEG_SLOPE * z0;
  z1 = (z1 >= 0.f) ? z1 : NEG_SLOPE * z1;
  float e0 = __expf(z0);
  float e1 = __expf(z1);
  EXC[SLOT[e]] = make_float2(e0, e1);
  atomicAdd(&denom[2 * t + 0], e0);
  atomicAdd(&denom[2 * t + 1], e1);
}

// ---------------------------------------------------------------------------
// Aggregation: one wave per node. lane holds float2 at k=2*lane of 128-vec.
// CSR arrays SS (source node) and EXC (exp pair) are read linearly.
// LAYER==1: out = max(agg + skip + b, 0) -> (N,128)  [relu(elu(z)) == relu(z)]
// LAYER==2: out = 0.5*(z_h0 + z_h1) + b  -> (N,64)
// ---------------------------------------------------------------------------
template <int LAYER>
__global__ __launch_bounds__(256) void aggregate(
    const int* __restrict__ rowptr, const int* __restrict__ SS,
    const float2* __restrict__ EXC, const float* __restrict__ denom,
    const float* __restrict__ P, const float* __restrict__ S,
    const float* __restrict__ bias, float* __restrict__ Out, int Nn) {
  int wid = (int)((blockIdx.x * blockDim.x + threadIdx.x) >> 6);
  int lane = threadIdx.x & 63;
  if (wid >= Nn) return;
  int n = wid;
  bool hi = lane >= 32;
  float dh = denom[2 * n + (hi ? 1 : 0)] + 1e-16f;
  float inv = 1.0f / dh;
  int beg = rowptr[n];
  int end = rowptr[n + 1];
  float accx = 0.f, accy = 0.f;
  for (int i = beg; i < end; ++i) {
    int s = SS[i];
    float2 exv = EXC[i];
    float att = (hi ? exv.y : exv.x) * inv;
    float2 v = *(const float2*)&P[(size_t)s * 128 + lane * 2];
    accx = fmaf(v.x, att, accx);
    accy = fmaf(v.y, att, accy);
  }
  float2 sk = *(const float2*)&S[(size_t)n * 128 + lane * 2];
  if (LAYER == 1) {
    float2 b = *(const float2*)&bias[lane * 2];
    float zx = fmaxf(accx + sk.x + b.x, 0.f);
    float zy = fmaxf(accy + sk.y + b.y, 0.f);
    float2 o = make_float2(zx, zy);
    *(float2*)&Out[(size_t)n * 128 + lane * 2] = o;
  } else {
    float zx = accx + sk.x;
    float zy = accy + sk.y;
    float ox = __shfl(zx, lane + 32, 64);
    float oy = __shfl(zy, lane + 32, 64);
    if (lane < 32) {
      float2 b = *(const float2*)&bias[lane * 2];
      float rx = 0.5f * (zx + ox) + b.x;
      float ry = 0.5f * (zy + oy) + b.y;
      float2 o = make_float2(rx, ry);
      *(float2*)&Out[(size_t)n * 64 + lane * 2] = o;
    }
  }
}

// ---------------------------------------------------------------------------
extern "C" void kernel_launch(void* const* d_in, const int* in_sizes, int n_in,
                              void* d_out, int out_size, void* d_ws,
                              size_t ws_size, hipStream_t stream) {
  const float* x = (const float*)d_in[0];
  const int* ei = (const int*)d_in[1];
  const float* W0 = (const float*)d_in[2];
  const float* a_src0 = (const float*)d_in[3];
  const float* a_trg0 = (const float*)d_in[4];
  const float* Wsk0 = (const float*)d_in[5];
  const float* b0 = (const float*)d_in[6];
  const float* W2 = (const float*)d_in[7];
  const float* a_src2 = (const float*)d_in[8];
  const float* a_trg2 = (const float*)d_in[9];
  const float* Wsk2 = (const float*)d_in[10];
  const float* b2 = (const float*)d_in[11];

  const int FIN = 256;
  const int N = in_sizes[0] / FIN;
  const int E = in_sizes[1] / 2;
  const int* src = ei;
  const int* trg = ei + E;

  char* base = (char*)d_ws;
  size_t off = 0;
  auto alloc = [&](size_t bytes) -> void* {
    void* p = base + off;
    off += (bytes + 255) & ~(size_t)255;
    return p;
  };
  float* P = (float*)alloc((size_t)N * 128 * sizeof(float));
  float* S = (float*)alloc((size_t)N * 128 * sizeof(float));
  float2* EXC = (float2*)alloc((size_t)E * sizeof(float2));
  int* SS = (int*)alloc((size_t)E * sizeof(int));
  int* SLOT = (int*)alloc((size_t)E * sizeof(int));
  float* ssrc = (float*)alloc((size_t)N * 2 * sizeof(float));
  float* strg = (float*)alloc((size_t)N * 2 * sizeof(float));
  int* rowptr = (int*)alloc((size_t)(N + 1) * sizeof(int));
  int* cursor = (int*)alloc((size_t)N * sizeof(int));
  size_t zbytes = (size_t)N * 4 + (size_t)N * 16;
  char* zbase = (char*)alloc(zbytes);
  int* deg = (int*)zbase;
  float* denom1 = (float*)(zbase + (size_t)N * 4);
  float* denom2 = denom1 + (size_t)N * 2;

  hipMemsetAsync(zbase, 0, zbytes, stream);

  dim3 blk(256);
  int gemmBlocks = (N + 63) / 64;
  int edgeBlocks = (E + 255) / 256;
  int nodeBlocks = (N + 3) / 4;

  // ---- layer 1 ----
  gemm_nk128<<<gemmBlocks, blk, 0, stream>>>(x, W0, P, N, FIN);
  gemm_nk128<<<gemmBlocks, blk, 0, stream>>>(x, Wsk0, S, N, FIN);
  node_scores<<<nodeBlocks, blk, 0, stream>>>(P, a_src0, a_trg0, ssrc, strg, N);
  deg_count<<<edgeBlocks, blk, 0, stream>>>(trg, deg, E);
  scan_deg<<<1, blk, 0, stream>>>(deg, rowptr, cursor, N, E);
  edge_fuse1<<<edgeBlocks, blk, 0, stream>>>(src, trg, (const float2*)ssrc,
                                             (const float2*)strg, cursor, SS,
                                             SLOT, EXC, denom1, E);
  aggregate<1><<<nodeBlocks, blk, 0, stream>>>(rowptr, SS, EXC, denom1, P, S,
                                               b0, S, N);
  // ---- layer 2 (h lives in S) ----
  gemm_nk128<<<gemmBlocks, blk, 0, stream>>>(S, W2, P, N, 128);
  gemm_nk128<<<gemmBlocks, blk, 0, stream>>>(S, Wsk2, S, N, 128);  // in place
  node_scores<<<nodeBlocks, blk, 0, stream>>>(P, a_src2, a_trg2, ssrc, strg, N);
  edge_fuse2<<<edgeBlocks, blk, 0, stream>>>(src, trg, (const float2*)ssrc,
                                             (const float2*)strg, SLOT, EXC,
                                             denom2, E);
  aggregate<2><<<nodeBlocks, blk, 0, stream>>>(rowptr, SS, EXC, denom2, P, S,
                                               b2, (float*)d_out, N);
}

// Round 3
// 627.923 us; speedup vs baseline: 1.6860x; 1.1660x over previous
//
#include <hip/hip_runtime.h>

#define NEG_SLOPE 0.2f

// ---------------------------------------------------------------------------
// C[M x 128] = A[M x K] * B[K x 128], fp32, K multiple of 32.
// block = 256 threads; tile 64 rows x 128 cols; each thread 4 rows x 8 cols.
// Safe for in-place C==A when C has 128 cols and A rows are only read by the
// block that writes them (stores happen after the full K loop).
// ---------------------------------------------------------------------------
__global__ __launch_bounds__(256) void gemm_nk128(
    const float* __restrict__ A, const float* __restrict__ B,
    float* __restrict__ C, int M, int K) {
  __shared__ float As[32][64];
  __shared__ float Bs[32][128];
  const int tid = threadIdx.x;
  const int tr = tid >> 4;   // 0..15 -> rows tr*4..tr*4+3
  const int tc = tid & 15;   // 0..15 -> cols tc*4.. and 64+tc*4..
  const int row0 = blockIdx.x * 64;

  float acc[4][8];
#pragma unroll
  for (int r = 0; r < 4; ++r)
#pragma unroll
    for (int c = 0; c < 8; ++c) acc[r][c] = 0.f;

  for (int k0 = 0; k0 < K; k0 += 32) {
    // A tile 64x32 -> As[k][row] (transposed)
#pragma unroll
    for (int j = 0; j < 2; ++j) {
      int s = tid + j * 256;
      int row = s >> 3;
      int kq = (s & 7) << 2;
      int gr = row0 + row;
      float4 v = make_float4(0.f, 0.f, 0.f, 0.f);
      if (gr < M) v = *(const float4*)&A[(size_t)gr * K + k0 + kq];
      As[kq + 0][row] = v.x;
      As[kq + 1][row] = v.y;
      As[kq + 2][row] = v.z;
      As[kq + 3][row] = v.w;
    }
    // B tile 32x128
#pragma unroll
    for (int j = 0; j < 4; ++j) {
      int s = tid + j * 256;
      int kr = s >> 5;
      int cq = (s & 31) << 2;
      *(float4*)&Bs[kr][cq] = *(const float4*)&B[(size_t)(k0 + kr) * 128 + cq];
    }
    __syncthreads();
#pragma unroll
    for (int kk = 0; kk < 32; ++kk) {
      float4 a4 = *(const float4*)&As[kk][tr << 2];
      float4 bA = *(const float4*)&Bs[kk][tc << 2];
      float4 bB = *(const float4*)&Bs[kk][64 + (tc << 2)];
      float av[4] = {a4.x, a4.y, a4.z, a4.w};
      float bv[8] = {bA.x, bA.y, bA.z, bA.w, bB.x, bB.y, bB.z, bB.w};
#pragma unroll
      for (int r = 0; r < 4; ++r)
#pragma unroll
        for (int c = 0; c < 8; ++c) acc[r][c] = fmaf(av[r], bv[c], acc[r][c]);
    }
    __syncthreads();
  }
#pragma unroll
  for (int r = 0; r < 4; ++r) {
    int gr = row0 + (tr << 2) + r;
    if (gr < M) {
      float4 o0 = make_float4(acc[r][0], acc[r][1], acc[r][2], acc[r][3]);
      float4 o1 = make_float4(acc[r][4], acc[r][5], acc[r][6], acc[r][7]);
      *(float4*)&C[(size_t)gr * 128 + (tc << 2)] = o0;
      *(float4*)&C[(size_t)gr * 128 + 64 + (tc << 2)] = o1;
    }
  }
}

// ---------------------------------------------------------------------------
// Per-node attention-score prep: s_src[n][h] = sum_f P[n][h][f]*a_src[h][f]
// One wave per node; lane holds float2 at k = 2*lane of the 128-vector.
// ---------------------------------------------------------------------------
__global__ __launch_bounds__(256) void node_scores(
    const float* __restrict__ P, const float* __restrict__ a_src,
    const float* __restrict__ a_trg, float* __restrict__ ssrc,
    float* __restrict__ strg, int Nn) {
  int wid = (int)((blockIdx.x * blockDim.x + threadIdx.x) >> 6);
  int lane = threadIdx.x & 63;
  if (wid >= Nn) return;
  float2 p = *(const float2*)&P[(size_t)wid * 128 + lane * 2];
  float2 as = *(const float2*)&a_src[lane * 2];
  float2 at = *(const float2*)&a_trg[lane * 2];
  float vs = p.x * as.x + p.y * as.y;
  float vt = p.x * at.x + p.y * at.y;
#pragma unroll
  for (int m = 1; m < 32; m <<= 1) {
    vs += __shfl_xor(vs, m, 64);
    vt += __shfl_xor(vt, m, 64);
  }
  if (lane == 0) {
    ssrc[wid * 2 + 0] = vs;
    strg[wid * 2 + 0] = vt;
  }
  if (lane == 32) {
    ssrc[wid * 2 + 1] = vs;
    strg[wid * 2 + 1] = vt;
  }
}

__global__ __launch_bounds__(256) void deg_count(const int* __restrict__ trg,
                                                 int* __restrict__ deg, int E) {
  int e = blockIdx.x * blockDim.x + threadIdx.x;
  if (e < E) atomicAdd(&deg[trg[e]], 1);
}

// ---------------------------------------------------------------------------
// Parallel exclusive scan of deg[N] -> rowptr/cursor, 3 phases.
// T = SCAN_BLOCKS*256 threads; each owns a contiguous chunk of deg.
// ---------------------------------------------------------------------------
#define SCAN_BLOCKS 64

__global__ __launch_bounds__(256) void scan_part(const int* __restrict__ deg,
                                                 int* __restrict__ tsum,
                                                 int Nn) {
  int gtid = blockIdx.x * 256 + threadIdx.x;
  int T = SCAN_BLOCKS * 256;
  int chunk = (Nn + T - 1) / T;
  int lo = gtid * chunk;
  int hi = lo + chunk;
  if (hi > Nn) hi = Nn;
  int s = 0;
  for (int i = lo; i < hi; ++i) s += deg[i];
  tsum[gtid] = s;
}

// Single block: exclusive-scan tsum[T] in place (T = 16384, 64 per thread).
__global__ __launch_bounds__(256) void scan_mid(int* __restrict__ tsum) {
  __shared__ int partial[256];
  int tid = threadIdx.x;
  const int PER = SCAN_BLOCKS;  // 64 entries per thread
  int base = tid * PER;
  int s = 0;
#pragma unroll 4
  for (int i = 0; i < PER; ++i) s += tsum[base + i];
  partial[tid] = s;
  __syncthreads();
  if (tid == 0) {
    int run = 0;
    for (int i = 0; i < 256; ++i) {
      int v = partial[i];
      partial[i] = run;
      run += v;
    }
  }
  __syncthreads();
  int run = partial[tid];
  for (int i = 0; i < PER; ++i) {
    int v = tsum[base + i];
    tsum[base + i] = run;
    run += v;
  }
}

__global__ __launch_bounds__(256) void scan_out(const int* __restrict__ deg,
                                                const int* __restrict__ tsum,
                                                int* __restrict__ rowptr,
                                                int* __restrict__ cursor,
                                                int Nn, int E) {
  int gtid = blockIdx.x * 256 + threadIdx.x;
  int T = SCAN_BLOCKS * 256;
  int chunk = (Nn + T - 1) / T;
  int lo = gtid * chunk;
  int hi = lo + chunk;
  if (hi > Nn) hi = Nn;
  int run = tsum[gtid];
  for (int i = lo; i < hi; ++i) {
    rowptr[i] = run;
    cursor[i] = run;
    run += deg[i];
  }
  if (gtid == 0) rowptr[Nn] = E;
}

// ---------------------------------------------------------------------------
// Layer-1 fused edge pass: score -> leaky_relu -> exp (global max shift
// cancels exactly in exp/sum-exp) -> CSR fill (SS + exp in CSR order) ->
// denom atomics. Records SLOT[e] so layer 2 reuses the CSR structure.
// ---------------------------------------------------------------------------
__global__ __launch_bounds__(256) void edge_fuse1(
    const int* __restrict__ src, const int* __restrict__ trg,
    const float2* __restrict__ ssrc, const float2* __restrict__ strg,
    int* __restrict__ cursor, int* __restrict__ SS, int* __restrict__ SLOT,
    float2* __restrict__ EXC, float* __restrict__ denom, int E) {
  int e = blockIdx.x * blockDim.x + threadIdx.x;
  if (e >= E) return;
  int s = src[e];
  int t = trg[e];
  float2 vs = ssrc[s];
  float2 vt = strg[t];
  float z0 = vs.x + vt.x;
  float z1 = vs.y + vt.y;
  z0 = (z0 >= 0.f) ? z0 : NEG_SLOPE * z0;
  z1 = (z1 >= 0.f) ? z1 : NEG_SLOPE * z1;
  float e0 = __expf(z0);
  float e1 = __expf(z1);
  int p = atomicAdd(&cursor[t], 1);
  SS[p] = s;
  SLOT[e] = p;
  EXC[p] = make_float2(e0, e1);
  atomicAdd(&denom[2 * t + 0], e0);
  atomicAdd(&denom[2 * t + 1], e1);
}

// Layer-2 fused edge pass: reuses CSR slots from layer 1.
__global__ __launch_bounds__(256) void edge_fuse2(
    const int* __restrict__ src, const int* __restrict__ trg,
    const float2* __restrict__ ssrc, const float2* __restrict__ strg,
    const int* __restrict__ SLOT, float2* __restrict__ EXC,
    float* __restrict__ denom, int E) {
  int e = blockIdx.x * blockDim.x + threadIdx.x;
  if (e >= E) return;
  int s = src[e];
  int t = trg[e];
  float2 vs = ssrc[s];
  float2 vt = strg[t];
  float z0 = vs.x + vt.x;
  float z1 = vs.y + vt.y;
  z0 = (z0 >= 0.f) ? z0 : NEG_SLOPE * z0;
  z1 = (z1 >= 0.f) ? z1 : NEG_SLOPE * z1;
  float e0 = __expf(z0);
  float e1 = __expf(z1);
  EXC[SLOT[e]] = make_float2(e0, e1);
  atomicAdd(&denom[2 * t + 0], e0);
  atomicAdd(&denom[2 * t + 1], e1);
}

// ---------------------------------------------------------------------------
// Aggregation: one wave per node. lane holds float2 at k=2*lane of 128-vec.
// CSR arrays SS (source node) and EXC (exp pair) are read linearly.
// LAYER==1: out = max(agg + skip + b, 0) -> (N,128)  [relu(elu(z)) == relu(z)]
// LAYER==2: out = 0.5*(z_h0 + z_h1) + b  -> (N,64)
// ---------------------------------------------------------------------------
template <int LAYER>
__global__ __launch_bounds__(256) void aggregate(
    const int* __restrict__ rowptr, const int* __restrict__ SS,
    const float2* __restrict__ EXC, const float* __restrict__ denom,
    const float* __restrict__ P, const float* __restrict__ S,
    const float* __restrict__ bias, float* __restrict__ Out, int Nn) {
  int wid = (int)((blockIdx.x * blockDim.x + threadIdx.x) >> 6);
  int lane = threadIdx.x & 63;
  if (wid >= Nn) return;
  int n = wid;
  bool hi = lane >= 32;
  float dh = denom[2 * n + (hi ? 1 : 0)] + 1e-16f;
  float inv = 1.0f / dh;
  int beg = rowptr[n];
  int end = rowptr[n + 1];
  float accx = 0.f, accy = 0.f;
  for (int i = beg; i < end; ++i) {
    int s = SS[i];
    float2 exv = EXC[i];
    float att = (hi ? exv.y : exv.x) * inv;
    float2 v = *(const float2*)&P[(size_t)s * 128 + lane * 2];
    accx = fmaf(v.x, att, accx);
    accy = fmaf(v.y, att, accy);
  }
  float2 sk = *(const float2*)&S[(size_t)n * 128 + lane * 2];
  if (LAYER == 1) {
    float2 b = *(const float2*)&bias[lane * 2];
    float zx = fmaxf(accx + sk.x + b.x, 0.f);
    float zy = fmaxf(accy + sk.y + b.y, 0.f);
    float2 o = make_float2(zx, zy);
    *(float2*)&Out[(size_t)n * 128 + lane * 2] = o;
  } else {
    float zx = accx + sk.x;
    float zy = accy + sk.y;
    float ox = __shfl(zx, lane + 32, 64);
    float oy = __shfl(zy, lane + 32, 64);
    if (lane < 32) {
      float2 b = *(const float2*)&bias[lane * 2];
      float rx = 0.5f * (zx + ox) + b.x;
      float ry = 0.5f * (zy + oy) + b.y;
      float2 o = make_float2(rx, ry);
      *(float2*)&Out[(size_t)n * 64 + lane * 2] = o;
    }
  }
}

// ---------------------------------------------------------------------------
extern "C" void kernel_launch(void* const* d_in, const int* in_sizes, int n_in,
                              void* d_out, int out_size, void* d_ws,
                              size_t ws_size, hipStream_t stream) {
  const float* x = (const float*)d_in[0];
  const int* ei = (const int*)d_in[1];
  const float* W0 = (const float*)d_in[2];
  const float* a_src0 = (const float*)d_in[3];
  const float* a_trg0 = (const float*)d_in[4];
  const float* Wsk0 = (const float*)d_in[5];
  const float* b0 = (const float*)d_in[6];
  const float* W2 = (const float*)d_in[7];
  const float* a_src2 = (const float*)d_in[8];
  const float* a_trg2 = (const float*)d_in[9];
  const float* Wsk2 = (const float*)d_in[10];
  const float* b2 = (const float*)d_in[11];

  const int FIN = 256;
  const int N = in_sizes[0] / FIN;
  const int E = in_sizes[1] / 2;
  const int* src = ei;
  const int* trg = ei + E;

  char* base = (char*)d_ws;
  size_t off = 0;
  auto alloc = [&](size_t bytes) -> void* {
    void* p = base + off;
    off += (bytes + 255) & ~(size_t)255;
    return p;
  };
  float* P = (float*)alloc((size_t)N * 128 * sizeof(float));
  float* S = (float*)alloc((size_t)N * 128 * sizeof(float));
  float2* EXC = (float2*)alloc((size_t)E * sizeof(float2));
  int* SS = (int*)alloc((size_t)E * sizeof(int));
  int* SLOT = (int*)alloc((size_t)E * sizeof(int));
  float* ssrc = (float*)alloc((size_t)N * 2 * sizeof(float));
  float* strg = (float*)alloc((size_t)N * 2 * sizeof(float));
  int* rowptr = (int*)alloc((size_t)(N + 1) * sizeof(int));
  int* cursor = (int*)alloc((size_t)N * sizeof(int));
  int* tsum = (int*)alloc((size_t)SCAN_BLOCKS * 256 * sizeof(int));
  size_t zbytes = (size_t)N * 4 + (size_t)N * 16;
  char* zbase = (char*)alloc(zbytes);
  int* deg = (int*)zbase;
  float* denom1 = (float*)(zbase + (size_t)N * 4);
  float* denom2 = denom1 + (size_t)N * 2;

  hipMemsetAsync(zbase, 0, zbytes, stream);

  dim3 blk(256);
  int gemmBlocks = (N + 63) / 64;
  int edgeBlocks = (E + 255) / 256;
  int nodeBlocks = (N + 3) / 4;

  // ---- layer 1 ----
  gemm_nk128<<<gemmBlocks, blk, 0, stream>>>(x, W0, P, N, FIN);
  gemm_nk128<<<gemmBlocks, blk, 0, stream>>>(x, Wsk0, S, N, FIN);
  node_scores<<<nodeBlocks, blk, 0, stream>>>(P, a_src0, a_trg0, ssrc, strg, N);
  deg_count<<<edgeBlocks, blk, 0, stream>>>(trg, deg, E);
  scan_part<<<SCAN_BLOCKS, blk, 0, stream>>>(deg, tsum, N);
  scan_mid<<<1, blk, 0, stream>>>(tsum);
  scan_out<<<SCAN_BLOCKS, blk, 0, stream>>>(deg, tsum, rowptr, cursor, N, E);
  edge_fuse1<<<edgeBlocks, blk, 0, stream>>>(src, trg, (const float2*)ssrc,
                                             (const float2*)strg, cursor, SS,
                                             SLOT, EXC, denom1, E);
  aggregate<1><<<nodeBlocks, blk, 0, stream>>>(rowptr, SS, EXC, denom1, P, S,
                                               b0, S, N);
  // ---- layer 2 (h lives in S) ----
  gemm_nk128<<<gemmBlocks, blk, 0, stream>>>(S, W2, P, N, 128);
  gemm_nk128<<<gemmBlocks, blk, 0, stream>>>(S, Wsk2, S, N, 128);  // in place
  node_scores<<<nodeBlocks, blk, 0, stream>>>(P, a_src2, a_trg2, ssrc, strg, N);
  edge_fuse2<<<edgeBlocks, blk, 0, stream>>>(src, trg, (const float2*)ssrc,
                                             (const float2*)strg, SLOT, EXC,
                                             denom2, E);
  aggregate<2><<<nodeBlocks, blk, 0, stream>>>(rowptr, SS, EXC, denom2, P, S,
                                               b2, (float*)d_out, N);
}

// Round 4
// 482.789 us; speedup vs baseline: 2.1928x; 1.3006x over previous
//
#include <hip/hip_runtime.h>

#define NEG_SLOPE 0.2f

// ---------------------------------------------------------------------------
// C[M x 128] = A[M x K] * B[K x 128], fp32, K multiple of 32.
// block = 256 threads; tile 64 rows x 128 cols; each thread 4 rows x 8 cols.
// Safe for in-place C==A when C has 128 cols and A rows are only read by the
// block that writes them (stores happen after the full K loop).
// ---------------------------------------------------------------------------
__global__ __launch_bounds__(256) void gemm_nk128(
    const float* __restrict__ A, const float* __restrict__ B,
    float* __restrict__ C, int M, int K) {
  __shared__ float As[32][64];
  __shared__ float Bs[32][128];
  const int tid = threadIdx.x;
  const int tr = tid >> 4;   // 0..15 -> rows tr*4..tr*4+3
  const int tc = tid & 15;   // 0..15 -> cols tc*4.. and 64+tc*4..
  const int row0 = blockIdx.x * 64;

  float acc[4][8];
#pragma unroll
  for (int r = 0; r < 4; ++r)
#pragma unroll
    for (int c = 0; c < 8; ++c) acc[r][c] = 0.f;

  for (int k0 = 0; k0 < K; k0 += 32) {
    // A tile 64x32 -> As[k][row] (transposed)
#pragma unroll
    for (int j = 0; j < 2; ++j) {
      int s = tid + j * 256;
      int row = s >> 3;
      int kq = (s & 7) << 2;
      int gr = row0 + row;
      float4 v = make_float4(0.f, 0.f, 0.f, 0.f);
      if (gr < M) v = *(const float4*)&A[(size_t)gr * K + k0 + kq];
      As[kq + 0][row] = v.x;
      As[kq + 1][row] = v.y;
      As[kq + 2][row] = v.z;
      As[kq + 3][row] = v.w;
    }
    // B tile 32x128
#pragma unroll
    for (int j = 0; j < 4; ++j) {
      int s = tid + j * 256;
      int kr = s >> 5;
      int cq = (s & 31) << 2;
      *(float4*)&Bs[kr][cq] = *(const float4*)&B[(size_t)(k0 + kr) * 128 + cq];
    }
    __syncthreads();
#pragma unroll
    for (int kk = 0; kk < 32; ++kk) {
      float4 a4 = *(const float4*)&As[kk][tr << 2];
      float4 bA = *(const float4*)&Bs[kk][tc << 2];
      float4 bB = *(const float4*)&Bs[kk][64 + (tc << 2)];
      float av[4] = {a4.x, a4.y, a4.z, a4.w};
      float bv[8] = {bA.x, bA.y, bA.z, bA.w, bB.x, bB.y, bB.z, bB.w};
#pragma unroll
      for (int r = 0; r < 4; ++r)
#pragma unroll
        for (int c = 0; c < 8; ++c) acc[r][c] = fmaf(av[r], bv[c], acc[r][c]);
    }
    __syncthreads();
  }
#pragma unroll
  for (int r = 0; r < 4; ++r) {
    int gr = row0 + (tr << 2) + r;
    if (gr < M) {
      float4 o0 = make_float4(acc[r][0], acc[r][1], acc[r][2], acc[r][3]);
      float4 o1 = make_float4(acc[r][4], acc[r][5], acc[r][6], acc[r][7]);
      *(float4*)&C[(size_t)gr * 128 + (tc << 2)] = o0;
      *(float4*)&C[(size_t)gr * 128 + 64 + (tc << 2)] = o1;
    }
  }
}

// ---------------------------------------------------------------------------
// Per-node attention-score prep: s_src[n][h] = sum_f P[n][h][f]*a_src[h][f]
// One wave per node; lane holds float2 at k = 2*lane of the 128-vector.
// ---------------------------------------------------------------------------
__global__ __launch_bounds__(256) void node_scores(
    const float* __restrict__ P, const float* __restrict__ a_src,
    const float* __restrict__ a_trg, float* __restrict__ ssrc,
    float* __restrict__ strg, int Nn) {
  int wid = (int)((blockIdx.x * blockDim.x + threadIdx.x) >> 6);
  int lane = threadIdx.x & 63;
  if (wid >= Nn) return;
  float2 p = *(const float2*)&P[(size_t)wid * 128 + lane * 2];
  float2 as = *(const float2*)&a_src[lane * 2];
  float2 at = *(const float2*)&a_trg[lane * 2];
  float vs = p.x * as.x + p.y * as.y;
  float vt = p.x * at.x + p.y * at.y;
#pragma unroll
  for (int m = 1; m < 32; m <<= 1) {
    vs += __shfl_xor(vs, m, 64);
    vt += __shfl_xor(vt, m, 64);
  }
  if (lane == 0) {
    ssrc[wid * 2 + 0] = vs;
    strg[wid * 2 + 0] = vt;
  }
  if (lane == 32) {
    ssrc[wid * 2 + 1] = vs;
    strg[wid * 2 + 1] = vt;
  }
}

__global__ __launch_bounds__(256) void deg_count(const int* __restrict__ trg,
                                                 int* __restrict__ deg, int E) {
  int e = blockIdx.x * blockDim.x + threadIdx.x;
  if (e < E) atomicAdd(&deg[trg[e]], 1);
}

// ---------------------------------------------------------------------------
// Parallel exclusive scan of deg[N] -> rowptr/cursor, 3 phases.
// ---------------------------------------------------------------------------
#define SCAN_BLOCKS 64

__global__ __launch_bounds__(256) void scan_part(const int* __restrict__ deg,
                                                 int* __restrict__ tsum,
                                                 int Nn) {
  int gtid = blockIdx.x * 256 + threadIdx.x;
  int T = SCAN_BLOCKS * 256;
  int chunk = (Nn + T - 1) / T;
  int lo = gtid * chunk;
  int hi = lo + chunk;
  if (hi > Nn) hi = Nn;
  int s = 0;
  for (int i = lo; i < hi; ++i) s += deg[i];
  tsum[gtid] = s;
}

// Single block: exclusive-scan tsum[T] in place (T = 16384, 64 per thread).
__global__ __launch_bounds__(256) void scan_mid(int* __restrict__ tsum) {
  __shared__ int partial[256];
  int tid = threadIdx.x;
  const int PER = SCAN_BLOCKS;  // 64 entries per thread
  int base = tid * PER;
  int s = 0;
#pragma unroll 4
  for (int i = 0; i < PER; ++i) s += tsum[base + i];
  partial[tid] = s;
  __syncthreads();
  if (tid == 0) {
    int run = 0;
    for (int i = 0; i < 256; ++i) {
      int v = partial[i];
      partial[i] = run;
      run += v;
    }
  }
  __syncthreads();
  int run = partial[tid];
  for (int i = 0; i < PER; ++i) {
    int v = tsum[base + i];
    tsum[base + i] = run;
    run += v;
  }
}

__global__ __launch_bounds__(256) void scan_out(const int* __restrict__ deg,
                                                const int* __restrict__ tsum,
                                                int* __restrict__ rowptr,
                                                int* __restrict__ cursor,
                                                int Nn, int E) {
  int gtid = blockIdx.x * 256 + threadIdx.x;
  int T = SCAN_BLOCKS * 256;
  int chunk = (Nn + T - 1) / T;
  int lo = gtid * chunk;
  int hi = lo + chunk;
  if (hi > Nn) hi = Nn;
  int run = tsum[gtid];
  for (int i = lo; i < hi; ++i) {
    rowptr[i] = run;
    cursor[i] = run;
    run += deg[i];
  }
  if (gtid == 0) rowptr[Nn] = E;
}

// CSR fill: only the source-node index, 4B/edge scatter. Built once, used by
// both layers.
__global__ __launch_bounds__(256) void fill_csr(const int* __restrict__ src,
                                                const int* __restrict__ trg,
                                                int* __restrict__ cursor,
                                                int* __restrict__ SS, int E) {
  int e = blockIdx.x * blockDim.x + threadIdx.x;
  if (e < E) {
    int t = trg[e];
    int p = atomicAdd(&cursor[t], 1);
    SS[p] = src[e];
  }
}

// ---------------------------------------------------------------------------
// Fused aggregation: one wave per node n. For each incoming edge (CSR row),
// recompute the edge score from ssrc[s] (broadcast gather, L2-resident) +
// strg[n] (wave-uniform), leaky_relu, exp (global max shift cancels exactly),
// and accumulate BOTH the weighted message sum and the softmax denominator in
// one pass: out = (sum w*v) / (sum w + 1e-16). No edge-value scatter at all.
// lane holds float2 at k=2*lane of the 128-vec; head = lane>>5.
// LAYER==1: out = max(agg + skip + b, 0) -> (N,128)  [relu(elu(z)) == relu(z)]
// LAYER==2: out = 0.5*(z_h0 + z_h1) + b  -> (N,64)
// ---------------------------------------------------------------------------
template <int LAYER>
__global__ __launch_bounds__(256) void aggregate(
    const int* __restrict__ rowptr, const int* __restrict__ SS,
    const float2* __restrict__ ssrc, const float2* __restrict__ strg,
    const float* __restrict__ P, const float* __restrict__ S,
    const float* __restrict__ bias, float* __restrict__ Out, int Nn) {
  int wid = (int)((blockIdx.x * blockDim.x + threadIdx.x) >> 6);
  int lane = threadIdx.x & 63;
  if (wid >= Nn) return;
  int n = wid;
  bool hi = lane >= 32;
  float2 st = strg[n];
  float et = hi ? st.y : st.x;
  int beg = rowptr[n];
  int end = rowptr[n + 1];
  float accx = 0.f, accy = 0.f, dsum = 0.f;
  for (int i = beg; i < end; ++i) {
    int s = SS[i];
    float2 es = ssrc[s];
    float z = (hi ? es.y : es.x) + et;
    z = (z >= 0.f) ? z : NEG_SLOPE * z;
    float w = __expf(z);
    dsum += w;
    float2 v = *(const float2*)&P[(size_t)s * 128 + lane * 2];
    accx = fmaf(v.x, w, accx);
    accy = fmaf(v.y, w, accy);
  }
  float inv = 1.0f / (dsum + 1e-16f);
  accx *= inv;
  accy *= inv;
  float2 sk = *(const float2*)&S[(size_t)n * 128 + lane * 2];
  if (LAYER == 1) {
    float2 b = *(const float2*)&bias[lane * 2];
    float zx = fmaxf(accx + sk.x + b.x, 0.f);
    float zy = fmaxf(accy + sk.y + b.y, 0.f);
    float2 o = make_float2(zx, zy);
    *(float2*)&Out[(size_t)n * 128 + lane * 2] = o;
  } else {
    float zx = accx + sk.x;
    float zy = accy + sk.y;
    float ox = __shfl(zx, lane + 32, 64);
    float oy = __shfl(zy, lane + 32, 64);
    if (lane < 32) {
      float2 b = *(const float2*)&bias[lane * 2];
      float rx = 0.5f * (zx + ox) + b.x;
      float ry = 0.5f * (zy + oy) + b.y;
      float2 o = make_float2(rx, ry);
      *(float2*)&Out[(size_t)n * 64 + lane * 2] = o;
    }
  }
}

// ---------------------------------------------------------------------------
extern "C" void kernel_launch(void* const* d_in, const int* in_sizes, int n_in,
                              void* d_out, int out_size, void* d_ws,
                              size_t ws_size, hipStream_t stream) {
  const float* x = (const float*)d_in[0];
  const int* ei = (const int*)d_in[1];
  const float* W0 = (const float*)d_in[2];
  const float* a_src0 = (const float*)d_in[3];
  const float* a_trg0 = (const float*)d_in[4];
  const float* Wsk0 = (const float*)d_in[5];
  const float* b0 = (const float*)d_in[6];
  const float* W2 = (const float*)d_in[7];
  const float* a_src2 = (const float*)d_in[8];
  const float* a_trg2 = (const float*)d_in[9];
  const float* Wsk2 = (const float*)d_in[10];
  const float* b2 = (const float*)d_in[11];

  const int FIN = 256;
  const int N = in_sizes[0] / FIN;
  const int E = in_sizes[1] / 2;
  const int* src = ei;
  const int* trg = ei + E;

  char* base = (char*)d_ws;
  size_t off = 0;
  auto alloc = [&](size_t bytes) -> void* {
    void* p = base + off;
    off += (bytes + 255) & ~(size_t)255;
    return p;
  };
  float* P = (float*)alloc((size_t)N * 128 * sizeof(float));
  float* S = (float*)alloc((size_t)N * 128 * sizeof(float));
  int* SS = (int*)alloc((size_t)E * sizeof(int));
  float* ssrc = (float*)alloc((size_t)N * 2 * sizeof(float));
  float* strg = (float*)alloc((size_t)N * 2 * sizeof(float));
  int* rowptr = (int*)alloc((size_t)(N + 1) * sizeof(int));
  int* cursor = (int*)alloc((size_t)N * sizeof(int));
  int* tsum = (int*)alloc((size_t)SCAN_BLOCKS * 256 * sizeof(int));
  int* deg = (int*)alloc((size_t)N * sizeof(int));

  hipMemsetAsync(deg, 0, (size_t)N * sizeof(int), stream);

  dim3 blk(256);
  int gemmBlocks = (N + 63) / 64;
  int edgeBlocks = (E + 255) / 256;
  int nodeBlocks = (N + 3) / 4;

  // ---- CSR build (graph structure, shared by both layers) ----
  deg_count<<<edgeBlocks, blk, 0, stream>>>(trg, deg, E);
  scan_part<<<SCAN_BLOCKS, blk, 0, stream>>>(deg, tsum, N);
  scan_mid<<<1, blk, 0, stream>>>(tsum);
  scan_out<<<SCAN_BLOCKS, blk, 0, stream>>>(deg, tsum, rowptr, cursor, N, E);
  fill_csr<<<edgeBlocks, blk, 0, stream>>>(src, trg, cursor, SS, E);

  // ---- layer 1 ----
  gemm_nk128<<<gemmBlocks, blk, 0, stream>>>(x, W0, P, N, FIN);
  gemm_nk128<<<gemmBlocks, blk, 0, stream>>>(x, Wsk0, S, N, FIN);
  node_scores<<<nodeBlocks, blk, 0, stream>>>(P, a_src0, a_trg0, ssrc, strg, N);
  aggregate<1><<<nodeBlocks, blk, 0, stream>>>(rowptr, SS, (const float2*)ssrc,
                                               (const float2*)strg, P, S, b0, S,
                                               N);
  // ---- layer 2 (h lives in S) ----
  gemm_nk128<<<gemmBlocks, blk, 0, stream>>>(S, W2, P, N, 128);
  gemm_nk128<<<gemmBlocks, blk, 0, stream>>>(S, Wsk2, S, N, 128);  // in place
  node_scores<<<nodeBlocks, blk, 0, stream>>>(P, a_src2, a_trg2, ssrc, strg, N);
  aggregate<2><<<nodeBlocks, blk, 0, stream>>>(rowptr, SS, (const float2*)ssrc,
                                               (const float2*)strg, P, S, b2,
                                               (float*)d_out, N);
}

// Round 5
// 374.224 us; speedup vs baseline: 2.8290x; 1.2901x over previous
//
#include <hip/hip_runtime.h>

#define NEG_SLOPE 0.2f

__device__ __forceinline__ unsigned short f2bf(float f) {
  unsigned u = __float_as_uint(f);
  unsigned r = (u + 0x7FFFu + ((u >> 16) & 1u)) >> 16;
  return (unsigned short)r;
}
__device__ __forceinline__ unsigned pack_bf16(float lo, float hi) {
  return (unsigned)f2bf(lo) | ((unsigned)f2bf(hi) << 16);
}

// ---------------------------------------------------------------------------
// C[M x 128] = A[M x K] * B[K x 128], fp32, K multiple of 32.
// block = 256 threads; tile 64 rows x 128 cols; each thread 4 rows x 8 cols.
// If WBF: also writes CH = packed bf16 copy of C (uint = elems {2j,2j+1}).
// Safe for in-place C==A (each block reads only the rows it writes; stores
// happen after the full K loop).
// ---------------------------------------------------------------------------
template <bool WBF>
__global__ __launch_bounds__(256) void gemm_nk128(
    const float* __restrict__ A, const float* __restrict__ B,
    float* __restrict__ C, unsigned* __restrict__ CH, int M, int K) {
  __shared__ float As[32][64];
  __shared__ float Bs[32][128];
  const int tid = threadIdx.x;
  const int tr = tid >> 4;   // 0..15 -> rows tr*4..tr*4+3
  const int tc = tid & 15;   // 0..15 -> cols tc*4.. and 64+tc*4..
  const int row0 = blockIdx.x * 64;

  float acc[4][8];
#pragma unroll
  for (int r = 0; r < 4; ++r)
#pragma unroll
    for (int c = 0; c < 8; ++c) acc[r][c] = 0.f;

  for (int k0 = 0; k0 < K; k0 += 32) {
#pragma unroll
    for (int j = 0; j < 2; ++j) {
      int s = tid + j * 256;
      int row = s >> 3;
      int kq = (s & 7) << 2;
      int gr = row0 + row;
      float4 v = make_float4(0.f, 0.f, 0.f, 0.f);
      if (gr < M) v = *(const float4*)&A[(size_t)gr * K + k0 + kq];
      As[kq + 0][row] = v.x;
      As[kq + 1][row] = v.y;
      As[kq + 2][row] = v.z;
      As[kq + 3][row] = v.w;
    }
#pragma unroll
    for (int j = 0; j < 4; ++j) {
      int s = tid + j * 256;
      int kr = s >> 5;
      int cq = (s & 31) << 2;
      *(float4*)&Bs[kr][cq] = *(const float4*)&B[(size_t)(k0 + kr) * 128 + cq];
    }
    __syncthreads();
#pragma unroll
    for (int kk = 0; kk < 32; ++kk) {
      float4 a4 = *(const float4*)&As[kk][tr << 2];
      float4 bA = *(const float4*)&Bs[kk][tc << 2];
      float4 bB = *(const float4*)&Bs[kk][64 + (tc << 2)];
      float av[4] = {a4.x, a4.y, a4.z, a4.w};
      float bv[8] = {bA.x, bA.y, bA.z, bA.w, bB.x, bB.y, bB.z, bB.w};
#pragma unroll
      for (int r = 0; r < 4; ++r)
#pragma unroll
        for (int c = 0; c < 8; ++c) acc[r][c] = fmaf(av[r], bv[c], acc[r][c]);
    }
    __syncthreads();
  }
#pragma unroll
  for (int r = 0; r < 4; ++r) {
    int gr = row0 + (tr << 2) + r;
    if (gr < M) {
      float4 o0 = make_float4(acc[r][0], acc[r][1], acc[r][2], acc[r][3]);
      float4 o1 = make_float4(acc[r][4], acc[r][5], acc[r][6], acc[r][7]);
      *(float4*)&C[(size_t)gr * 128 + (tc << 2)] = o0;
      *(float4*)&C[(size_t)gr * 128 + 64 + (tc << 2)] = o1;
      if (WBF) {
        uint2 h0 = make_uint2(pack_bf16(o0.x, o0.y), pack_bf16(o0.z, o0.w));
        uint2 h1 = make_uint2(pack_bf16(o1.x, o1.y), pack_bf16(o1.z, o1.w));
        *(uint2*)&CH[(size_t)gr * 64 + tc * 2] = h0;
        *(uint2*)&CH[(size_t)gr * 64 + 32 + tc * 2] = h1;
      }
    }
  }
}

// ---------------------------------------------------------------------------
// Per-node attention-score prep (fp32 P): one wave per node.
// ---------------------------------------------------------------------------
__global__ __launch_bounds__(256) void node_scores(
    const float* __restrict__ P, const float* __restrict__ a_src,
    const float* __restrict__ a_trg, float* __restrict__ ssrc,
    float* __restrict__ strg, int Nn) {
  int wid = (int)((blockIdx.x * blockDim.x + threadIdx.x) >> 6);
  int lane = threadIdx.x & 63;
  if (wid >= Nn) return;
  float2 p = *(const float2*)&P[(size_t)wid * 128 + lane * 2];
  float2 as = *(const float2*)&a_src[lane * 2];
  float2 at = *(const float2*)&a_trg[lane * 2];
  float vs = p.x * as.x + p.y * as.y;
  float vt = p.x * at.x + p.y * at.y;
#pragma unroll
  for (int m = 1; m < 32; m <<= 1) {
    vs += __shfl_xor(vs, m, 64);
    vt += __shfl_xor(vt, m, 64);
  }
  if (lane == 0) {
    ssrc[wid * 2 + 0] = vs;
    strg[wid * 2 + 0] = vt;
  }
  if (lane == 32) {
    ssrc[wid * 2 + 1] = vs;
    strg[wid * 2 + 1] = vt;
  }
}

__global__ __launch_bounds__(256) void deg_count(const int* __restrict__ trg,
                                                 int* __restrict__ deg, int E) {
  int e = blockIdx.x * blockDim.x + threadIdx.x;
  if (e < E) atomicAdd(&deg[trg[e]], 1);
}

// ---------------------------------------------------------------------------
// Parallel exclusive scan of deg[N] -> rowptr/cursor, 3 phases.
// ---------------------------------------------------------------------------
#define SCAN_BLOCKS 64

__global__ __launch_bounds__(256) void scan_part(const int* __restrict__ deg,
                                                 int* __restrict__ tsum,
                                                 int Nn) {
  int gtid = blockIdx.x * 256 + threadIdx.x;
  int T = SCAN_BLOCKS * 256;
  int chunk = (Nn + T - 1) / T;
  int lo = gtid * chunk;
  int hi = lo + chunk;
  if (hi > Nn) hi = Nn;
  int s = 0;
  for (int i = lo; i < hi; ++i) s += deg[i];
  tsum[gtid] = s;
}

__global__ __launch_bounds__(256) void scan_mid(int* __restrict__ tsum) {
  __shared__ int partial[256];
  int tid = threadIdx.x;
  const int PER = SCAN_BLOCKS;
  int base = tid * PER;
  int s = 0;
#pragma unroll 4
  for (int i = 0; i < PER; ++i) s += tsum[base + i];
  partial[tid] = s;
  __syncthreads();
  if (tid == 0) {
    int run = 0;
    for (int i = 0; i < 256; ++i) {
      int v = partial[i];
      partial[i] = run;
      run += v;
    }
  }
  __syncthreads();
  int run = partial[tid];
  for (int i = 0; i < PER; ++i) {
    int v = tsum[base + i];
    tsum[base + i] = run;
    run += v;
  }
}

__global__ __launch_bounds__(256) void scan_out(const int* __restrict__ deg,
                                                const int* __restrict__ tsum,
                                                int* __restrict__ rowptr,
                                                int* __restrict__ cursor,
                                                int Nn, int E) {
  int gtid = blockIdx.x * 256 + threadIdx.x;
  int T = SCAN_BLOCKS * 256;
  int chunk = (Nn + T - 1) / T;
  int lo = gtid * chunk;
  int hi = lo + chunk;
  if (hi > Nn) hi = Nn;
  int run = tsum[gtid];
  for (int i = lo; i < hi; ++i) {
    rowptr[i] = run;
    cursor[i] = run;
    run += deg[i];
  }
  if (gtid == 0) rowptr[Nn] = E;
}

__global__ __launch_bounds__(256) void fill_csr(const int* __restrict__ src,
                                                const int* __restrict__ trg,
                                                int* __restrict__ cursor,
                                                int* __restrict__ SS, int E) {
  int e = blockIdx.x * blockDim.x + threadIdx.x;
  if (e < E) {
    int t = trg[e];
    int p = atomicAdd(&cursor[t], 1);
    SS[p] = src[e];
  }
}

// ---------------------------------------------------------------------------
// Fused aggregation: one wave per node. Edge weights recomputed on the fly
// (ssrc[s] broadcast + strg[n] uniform -> leaky_relu -> exp; global max shift
// cancels). Messages gathered from packed-bf16 PH (uint = 2 elems per lane).
// CSR indices fetched 64-at-a-time (SS[base+lane]) and broadcast via
// readlane; 4 edges in flight to overlap gather latency.
// LAYER==1: out = max(agg + skip + b, 0) -> (N,128)
// LAYER==2: out = 0.5*(z_h0 + z_h1) + b  -> (N,64)
// ---------------------------------------------------------------------------
template <int LAYER>
__global__ __launch_bounds__(256) void aggregate(
    const int* __restrict__ rowptr, const int* __restrict__ SS,
    const float2* __restrict__ ssrc, const float2* __restrict__ strg,
    const unsigned* __restrict__ PH, const float* __restrict__ S,
    const float* __restrict__ bias, float* __restrict__ Out, int Nn) {
  int wid = (int)((blockIdx.x * blockDim.x + threadIdx.x) >> 6);
  int lane = threadIdx.x & 63;
  if (wid >= Nn) return;
  int n = wid;
  bool hi = lane >= 32;
  float2 st = strg[n];
  float et = hi ? st.y : st.x;
  int beg = rowptr[n];
  int end = rowptr[n + 1];
  float accx = 0.f, accy = 0.f, dsum = 0.f;

  for (int base = beg; base < end; base += 64) {
    int cnt = end - base;
    if (cnt > 64) cnt = 64;
    int idx = base + lane;
    int sv = (idx < end) ? SS[idx] : 0;
    int j = 0;
    for (; j + 4 <= cnt; j += 4) {
      int s0 = __builtin_amdgcn_readlane(sv, j + 0);
      int s1 = __builtin_amdgcn_readlane(sv, j + 1);
      int s2 = __builtin_amdgcn_readlane(sv, j + 2);
      int s3 = __builtin_amdgcn_readlane(sv, j + 3);
      unsigned w0 = PH[(size_t)s0 * 64 + lane];
      unsigned w1 = PH[(size_t)s1 * 64 + lane];
      unsigned w2 = PH[(size_t)s2 * 64 + lane];
      unsigned w3 = PH[(size_t)s3 * 64 + lane];
      float2 e0 = ssrc[s0];
      float2 e1 = ssrc[s1];
      float2 e2 = ssrc[s2];
      float2 e3 = ssrc[s3];
      float z0 = (hi ? e0.y : e0.x) + et;
      float z1 = (hi ? e1.y : e1.x) + et;
      float z2 = (hi ? e2.y : e2.x) + et;
      float z3 = (hi ? e3.y : e3.x) + et;
      z0 = (z0 >= 0.f) ? z0 : NEG_SLOPE * z0;
      z1 = (z1 >= 0.f) ? z1 : NEG_SLOPE * z1;
      z2 = (z2 >= 0.f) ? z2 : NEG_SLOPE * z2;
      z3 = (z3 >= 0.f) ? z3 : NEG_SLOPE * z3;
      float g0 = __expf(z0), g1 = __expf(z1), g2 = __expf(z2), g3 = __expf(z3);
      dsum += (g0 + g1) + (g2 + g3);
      accx = fmaf(__uint_as_float(w0 << 16), g0, accx);
      accy = fmaf(__uint_as_float(w0 & 0xFFFF0000u), g0, accy);
      accx = fmaf(__uint_as_float(w1 << 16), g1, accx);
      accy = fmaf(__uint_as_float(w1 & 0xFFFF0000u), g1, accy);
      accx = fmaf(__uint_as_float(w2 << 16), g2, accx);
      accy = fmaf(__uint_as_float(w2 & 0xFFFF0000u), g2, accy);
      accx = fmaf(__uint_as_float(w3 << 16), g3, accx);
      accy = fmaf(__uint_as_float(w3 & 0xFFFF0000u), g3, accy);
    }
    for (; j < cnt; ++j) {
      int s0 = __builtin_amdgcn_readlane(sv, j);
      unsigned w0 = PH[(size_t)s0 * 64 + lane];
      float2 e0 = ssrc[s0];
      float z0 = (hi ? e0.y : e0.x) + et;
      z0 = (z0 >= 0.f) ? z0 : NEG_SLOPE * z0;
      float g0 = __expf(z0);
      dsum += g0;
      accx = fmaf(__uint_as_float(w0 << 16), g0, accx);
      accy = fmaf(__uint_as_float(w0 & 0xFFFF0000u), g0, accy);
    }
  }

  float inv = 1.0f / (dsum + 1e-16f);
  accx *= inv;
  accy *= inv;
  float2 sk = *(const float2*)&S[(size_t)n * 128 + lane * 2];
  if (LAYER == 1) {
    float2 b = *(const float2*)&bias[lane * 2];
    float zx = fmaxf(accx + sk.x + b.x, 0.f);
    float zy = fmaxf(accy + sk.y + b.y, 0.f);
    *(float2*)&Out[(size_t)n * 128 + lane * 2] = make_float2(zx, zy);
  } else {
    float zx = accx + sk.x;
    float zy = accy + sk.y;
    float ox = __shfl(zx, lane + 32, 64);
    float oy = __shfl(zy, lane + 32, 64);
    if (lane < 32) {
      float2 b = *(const float2*)&bias[lane * 2];
      float rx = 0.5f * (zx + ox) + b.x;
      float ry = 0.5f * (zy + oy) + b.y;
      *(float2*)&Out[(size_t)n * 64 + lane * 2] = make_float2(rx, ry);
    }
  }
}

// ---------------------------------------------------------------------------
extern "C" void kernel_launch(void* const* d_in, const int* in_sizes, int n_in,
                              void* d_out, int out_size, void* d_ws,
                              size_t ws_size, hipStream_t stream) {
  const float* x = (const float*)d_in[0];
  const int* ei = (const int*)d_in[1];
  const float* W0 = (const float*)d_in[2];
  const float* a_src0 = (const float*)d_in[3];
  const float* a_trg0 = (const float*)d_in[4];
  const float* Wsk0 = (const float*)d_in[5];
  const float* b0 = (const float*)d_in[6];
  const float* W2 = (const float*)d_in[7];
  const float* a_src2 = (const float*)d_in[8];
  const float* a_trg2 = (const float*)d_in[9];
  const float* Wsk2 = (const float*)d_in[10];
  const float* b2 = (const float*)d_in[11];

  const int FIN = 256;
  const int N = in_sizes[0] / FIN;
  const int E = in_sizes[1] / 2;
  const int* src = ei;
  const int* trg = ei + E;

  char* base = (char*)d_ws;
  size_t off = 0;
  auto alloc = [&](size_t bytes) -> void* {
    void* p = base + off;
    off += (bytes + 255) & ~(size_t)255;
    return p;
  };
  float* P = (float*)alloc((size_t)N * 128 * sizeof(float));
  float* S = (float*)alloc((size_t)N * 128 * sizeof(float));
  unsigned* PH = (unsigned*)alloc((size_t)N * 64 * sizeof(unsigned));
  int* SS = (int*)alloc((size_t)E * sizeof(int));
  float* ssrc = (float*)alloc((size_t)N * 2 * sizeof(float));
  float* strg = (float*)alloc((size_t)N * 2 * sizeof(float));
  int* rowptr = (int*)alloc((size_t)(N + 1) * sizeof(int));
  int* cursor = (int*)alloc((size_t)N * sizeof(int));
  int* tsum = (int*)alloc((size_t)SCAN_BLOCKS * 256 * sizeof(int));
  int* deg = (int*)alloc((size_t)N * sizeof(int));

  hipMemsetAsync(deg, 0, (size_t)N * sizeof(int), stream);

  dim3 blk(256);
  int gemmBlocks = (N + 63) / 64;
  int edgeBlocks = (E + 255) / 256;
  int nodeBlocks = (N + 3) / 4;

  // ---- CSR build (graph structure, shared by both layers) ----
  deg_count<<<edgeBlocks, blk, 0, stream>>>(trg, deg, E);
  scan_part<<<SCAN_BLOCKS, blk, 0, stream>>>(deg, tsum, N);
  scan_mid<<<1, blk, 0, stream>>>(tsum);
  scan_out<<<SCAN_BLOCKS, blk, 0, stream>>>(deg, tsum, rowptr, cursor, N, E);
  fill_csr<<<edgeBlocks, blk, 0, stream>>>(src, trg, cursor, SS, E);

  // ---- layer 1 ----
  gemm_nk128<true><<<gemmBlocks, blk, 0, stream>>>(x, W0, P, PH, N, FIN);
  gemm_nk128<false><<<gemmBlocks, blk, 0, stream>>>(x, Wsk0, S, nullptr, N, FIN);
  node_scores<<<nodeBlocks, blk, 0, stream>>>(P, a_src0, a_trg0, ssrc, strg, N);
  aggregate<1><<<nodeBlocks, blk, 0, stream>>>(rowptr, SS, (const float2*)ssrc,
                                               (const float2*)strg, PH, S, b0,
                                               S, N);
  // ---- layer 2 (h lives in S) ----
  gemm_nk128<true><<<gemmBlocks, blk, 0, stream>>>(S, W2, P, PH, N, 128);
  gemm_nk128<false><<<gemmBlocks, blk, 0, stream>>>(S, Wsk2, S, nullptr, N, 128);
  node_scores<<<nodeBlocks, blk, 0, stream>>>(P, a_src2, a_trg2, ssrc, strg, N);
  aggregate<2><<<nodeBlocks, blk, 0, stream>>>(rowptr, SS, (const float2*)ssrc,
                                               (const float2*)strg, PH, S, b2,
                                               (float*)d_out, N);
}

// Round 6
// 268.042 us; speedup vs baseline: 3.9497x; 1.3961x over previous
//
#include <hip/hip_runtime.h>

#define NEG_SLOPE 0.2f

typedef __attribute__((ext_vector_type(8))) short short8;
typedef __attribute__((ext_vector_type(4))) float f32x4;

__device__ __forceinline__ unsigned short f2bf(float f) {
  unsigned u = __float_as_uint(f);
  unsigned r = (u + 0x7FFFu + ((u >> 16) & 1u)) >> 16;
  return (unsigned short)r;
}
__device__ __forceinline__ unsigned pack_bf16(float lo, float hi) {
  return (unsigned)f2bf(lo) | ((unsigned)f2bf(hi) << 16);
}

// ---------------------------------------------------------------------------
// W[K][128] fp32 -> Wt[128][K] bf16 (transpose+convert, run once per W).
// ---------------------------------------------------------------------------
__global__ __launch_bounds__(256) void wconv(const float* __restrict__ W,
                                             unsigned* __restrict__ Wt, int K) {
  int per = K >> 3;  // 8-k chunks per col
  int t = blockIdx.x * 256 + threadIdx.x;
  if (t >= 128 * per) return;
  int col = t / per;
  int kc = (t - col * per) << 3;
  float w[8];
#pragma unroll
  for (int j = 0; j < 8; ++j) w[j] = W[(size_t)(kc + j) * 128 + col];
  uint4 o = make_uint4(pack_bf16(w[0], w[1]), pack_bf16(w[2], w[3]),
                       pack_bf16(w[4], w[5]), pack_bf16(w[6], w[7]));
  *(uint4*)&Wt[((size_t)col * K + kc) >> 1] = o;
}

// ---------------------------------------------------------------------------
// bf16-MFMA GEMM: [M x K](fp32, cast) * [K x 128](bf16 Wt) -> 64x128 tiles.
// block = 256 (4 waves); wave w owns rows 16w..16w+15 (8 col-frags of 16).
// MODE 0 (skip): writes C fp32. Safe in-place C==A (stores after K loop, each
//   block only reads rows it writes).
// MODE 1 (proj): writes PH (packed bf16 pairs) + fused attention scores
//   ssrc/strg (dot with a_src/a_trg over the row, from LDS).
// mfma_f32_16x16x32_bf16 layouts (m89/m91 verified):
//   A: row=lane&15, k=(lane>>4)*8+i ; B: col=lane&15, same k
//   D: col=lane&15, row=(lane>>4)*4+reg
// ---------------------------------------------------------------------------
template <int MODE>
__global__ __launch_bounds__(256) void gemm_mfma(
    const float* __restrict__ A, const unsigned* __restrict__ Bt,
    float* __restrict__ C, unsigned* __restrict__ PH,
    const float* __restrict__ a_src, const float* __restrict__ a_trg,
    float* __restrict__ ssrc, float* __restrict__ strg, int M, int K) {
  __shared__ float Cs[64][132];  // epilogue buffer; staging aliases it
  unsigned short* lds = (unsigned short*)&Cs[0][0];
  unsigned short(*As)[40] = (unsigned short(*)[40])lds;             // 5120 B
  unsigned short(*Bs)[40] = (unsigned short(*)[40])(lds + 64 * 40); // 10240 B

  const int tid = threadIdx.x;
  const int lane = tid & 63;
  const int w = tid >> 6;
  const int row0 = blockIdx.x * 64;

  f32x4 acc[8];
#pragma unroll
  for (int c = 0; c < 8; ++c) acc[c] = (f32x4)0.f;

  const int arow = tid >> 2;       // 0..63
  const int akq = (tid & 3) << 3;  // 0,8,16,24
  const int bcol = tid >> 1;       // 0..127
  const int bh = (tid & 1) << 4;   // 0,16

  for (int k0 = 0; k0 < K; k0 += 32) {
    // A stage: 64x32 fp32 -> bf16 (zeros past M)
    {
      int gr = row0 + arow;
      float4 v0 = make_float4(0.f, 0.f, 0.f, 0.f), v1 = v0;
      if (gr < M) {
        v0 = *(const float4*)&A[(size_t)gr * K + k0 + akq];
        v1 = *(const float4*)&A[(size_t)gr * K + k0 + akq + 4];
      }
      uint4 p = make_uint4(pack_bf16(v0.x, v0.y), pack_bf16(v0.z, v0.w),
                           pack_bf16(v1.x, v1.y), pack_bf16(v1.z, v1.w));
      *(uint4*)&As[arow][akq] = p;
    }
    // B stage: Bt[col][k] bf16, 128x32 -> Bs
    {
      size_t base = ((size_t)bcol * K + k0 + bh) >> 1;
      uint4 p0 = *(const uint4*)&Bt[base];
      uint4 p1 = *(const uint4*)&Bt[base + 4];
      *(uint4*)&Bs[bcol][bh] = p0;
      *(uint4*)&Bs[bcol][bh + 8] = p1;
    }
    __syncthreads();
    short8 af = *(const short8*)&As[16 * w + (lane & 15)][(lane >> 4) << 3];
#pragma unroll
    for (int c = 0; c < 8; ++c) {
      short8 bf = *(const short8*)&Bs[16 * c + (lane & 15)][(lane >> 4) << 3];
      acc[c] = __builtin_amdgcn_mfma_f32_16x16x32_bf16(af, bf, acc[c], 0, 0, 0);
    }
    __syncthreads();
  }

  // acc -> Cs (D layout: row=(lane>>4)*4+r, col=16c+(lane&15))
#pragma unroll
  for (int c = 0; c < 8; ++c)
#pragma unroll
    for (int r = 0; r < 4; ++r)
      Cs[16 * w + ((lane >> 4) << 2) + r][16 * c + (lane & 15)] = acc[c][r];
  __syncthreads();

  // coalesced store pass: per wave 16 rows, 2 rows per iteration
  const int hrow = lane >> 5;
  const int c32 = lane & 31;
#pragma unroll
  for (int i = 0; i < 8; ++i) {
    int lr = 16 * w + 2 * i + hrow;
    int gr = row0 + lr;
    if (gr < M) {
      float4 v = *(const float4*)&Cs[lr][c32 * 4];
      if (MODE == 0) {
        *(float4*)&C[(size_t)gr * 128 + c32 * 4] = v;
      } else {
        *(uint2*)&PH[(size_t)gr * 64 + c32 * 2] =
            make_uint2(pack_bf16(v.x, v.y), pack_bf16(v.z, v.w));
      }
    }
  }

  if (MODE == 1) {
    // fused scores: thread t -> row=t>>2, quarter q=t&3 (cols q*32..+31).
    // q in {0,1}: head0, {2,3}: head1; pairwise shfl_xor(1) completes dots.
    int srow = tid >> 2;
    int q = tid & 3;
    int gr = row0 + srow;
    float ds = 0.f, dt = 0.f;
#pragma unroll
    for (int j = 0; j < 8; ++j) {
      int col = q * 32 + j * 4;
      float4 v = *(const float4*)&Cs[srow][col];
      float4 asv = *(const float4*)&a_src[col];
      float4 atv = *(const float4*)&a_trg[col];
      ds += v.x * asv.x + v.y * asv.y + v.z * asv.z + v.w * asv.w;
      dt += v.x * atv.x + v.y * atv.y + v.z * atv.z + v.w * atv.w;
    }
    ds += __shfl_xor(ds, 1, 64);
    dt += __shfl_xor(dt, 1, 64);
    if (gr < M && (q & 1) == 0) {
      int h = q >> 1;
      ssrc[gr * 2 + h] = ds;
      strg[gr * 2 + h] = dt;
    }
  }
}

__global__ __launch_bounds__(256) void deg_count(const int* __restrict__ trg,
                                                 int* __restrict__ deg, int E) {
  int e = blockIdx.x * blockDim.x + threadIdx.x;
  if (e < E) atomicAdd(&deg[trg[e]], 1);
}

// ---------------------------------------------------------------------------
// Parallel exclusive scan of deg[N] -> rowptr/cursor, 3 phases.
// ---------------------------------------------------------------------------
#define SCAN_BLOCKS 64

__global__ __launch_bounds__(256) void scan_part(const int* __restrict__ deg,
                                                 int* __restrict__ tsum,
                                                 int Nn) {
  int gtid = blockIdx.x * 256 + threadIdx.x;
  int T = SCAN_BLOCKS * 256;
  int chunk = (Nn + T - 1) / T;
  int lo = gtid * chunk;
  int hi = lo + chunk;
  if (hi > Nn) hi = Nn;
  int s = 0;
  for (int i = lo; i < hi; ++i) s += deg[i];
  tsum[gtid] = s;
}

__global__ __launch_bounds__(256) void scan_mid(int* __restrict__ tsum) {
  __shared__ int partial[256];
  int tid = threadIdx.x;
  const int PER = SCAN_BLOCKS;
  int base = tid * PER;
  int s = 0;
#pragma unroll 4
  for (int i = 0; i < PER; ++i) s += tsum[base + i];
  partial[tid] = s;
  __syncthreads();
  if (tid == 0) {
    int run = 0;
    for (int i = 0; i < 256; ++i) {
      int v = partial[i];
      partial[i] = run;
      run += v;
    }
  }
  __syncthreads();
  int run = partial[tid];
  for (int i = 0; i < PER; ++i) {
    int v = tsum[base + i];
    tsum[base + i] = run;
    run += v;
  }
}

__global__ __launch_bounds__(256) void scan_out(const int* __restrict__ deg,
                                                const int* __restrict__ tsum,
                                                int* __restrict__ rowptr,
                                                int* __restrict__ cursor,
                                                int Nn, int E) {
  int gtid = blockIdx.x * 256 + threadIdx.x;
  int T = SCAN_BLOCKS * 256;
  int chunk = (Nn + T - 1) / T;
  int lo = gtid * chunk;
  int hi = lo + chunk;
  if (hi > Nn) hi = Nn;
  int run = tsum[gtid];
  for (int i = lo; i < hi; ++i) {
    rowptr[i] = run;
    cursor[i] = run;
    run += deg[i];
  }
  if (gtid == 0) rowptr[Nn] = E;
}

__global__ __launch_bounds__(256) void fill_csr(const int* __restrict__ src,
                                                const int* __restrict__ trg,
                                                int* __restrict__ cursor,
                                                int* __restrict__ SS, int E) {
  int e = blockIdx.x * blockDim.x + threadIdx.x;
  if (e < E) {
    int t = trg[e];
    int p = atomicAdd(&cursor[t], 1);
    SS[p] = src[e];
  }
}

// ---------------------------------------------------------------------------
// Fused aggregation: one wave per node; weights recomputed on the fly; bf16
// messages from PH; CSR indices wave-loaded + readlane broadcast; 4 edges in
// flight. LAYER==1: out=max(agg+skip+b,0) (N,128). LAYER==2: head-mean (N,64).
// ---------------------------------------------------------------------------
template <int LAYER>
__global__ __launch_bounds__(256) void aggregate(
    const int* __restrict__ rowptr, const int* __restrict__ SS,
    const float2* __restrict__ ssrc, const float2* __restrict__ strg,
    const unsigned* __restrict__ PH, const float* __restrict__ S,
    const float* __restrict__ bias, float* __restrict__ Out, int Nn) {
  int wid = (int)((blockIdx.x * blockDim.x + threadIdx.x) >> 6);
  int lane = threadIdx.x & 63;
  if (wid >= Nn) return;
  int n = wid;
  bool hi = lane >= 32;
  float2 st = strg[n];
  float et = hi ? st.y : st.x;
  int beg = rowptr[n];
  int end = rowptr[n + 1];
  float accx = 0.f, accy = 0.f, dsum = 0.f;

  for (int base = beg; base < end; base += 64) {
    int cnt = end - base;
    if (cnt > 64) cnt = 64;
    int idx = base + lane;
    int sv = (idx < end) ? SS[idx] : 0;
    int j = 0;
    for (; j + 4 <= cnt; j += 4) {
      int s0 = __builtin_amdgcn_readlane(sv, j + 0);
      int s1 = __builtin_amdgcn_readlane(sv, j + 1);
      int s2 = __builtin_amdgcn_readlane(sv, j + 2);
      int s3 = __builtin_amdgcn_readlane(sv, j + 3);
      unsigned w0 = PH[(size_t)s0 * 64 + lane];
      unsigned w1 = PH[(size_t)s1 * 64 + lane];
      unsigned w2 = PH[(size_t)s2 * 64 + lane];
      unsigned w3 = PH[(size_t)s3 * 64 + lane];
      float2 e0 = ssrc[s0];
      float2 e1 = ssrc[s1];
      float2 e2 = ssrc[s2];
      float2 e3 = ssrc[s3];
      float z0 = (hi ? e0.y : e0.x) + et;
      float z1 = (hi ? e1.y : e1.x) + et;
      float z2 = (hi ? e2.y : e2.x) + et;
      float z3 = (hi ? e3.y : e3.x) + et;
      z0 = (z0 >= 0.f) ? z0 : NEG_SLOPE * z0;
      z1 = (z1 >= 0.f) ? z1 : NEG_SLOPE * z1;
      z2 = (z2 >= 0.f) ? z2 : NEG_SLOPE * z2;
      z3 = (z3 >= 0.f) ? z3 : NEG_SLOPE * z3;
      float g0 = __expf(z0), g1 = __expf(z1), g2 = __expf(z2), g3 = __expf(z3);
      dsum += (g0 + g1) + (g2 + g3);
      accx = fmaf(__uint_as_float(w0 << 16), g0, accx);
      accy = fmaf(__uint_as_float(w0 & 0xFFFF0000u), g0, accy);
      accx = fmaf(__uint_as_float(w1 << 16), g1, accx);
      accy = fmaf(__uint_as_float(w1 & 0xFFFF0000u), g1, accy);
      accx = fmaf(__uint_as_float(w2 << 16), g2, accx);
      accy = fmaf(__uint_as_float(w2 & 0xFFFF0000u), g2, accy);
      accx = fmaf(__uint_as_float(w3 << 16), g3, accx);
      accy = fmaf(__uint_as_float(w3 & 0xFFFF0000u), g3, accy);
    }
    for (; j < cnt; ++j) {
      int s0 = __builtin_amdgcn_readlane(sv, j);
      unsigned w0 = PH[(size_t)s0 * 64 + lane];
      float2 e0 = ssrc[s0];
      float z0 = (hi ? e0.y : e0.x) + et;
      z0 = (z0 >= 0.f) ? z0 : NEG_SLOPE * z0;
      float g0 = __expf(z0);
      dsum += g0;
      accx = fmaf(__uint_as_float(w0 << 16), g0, accx);
      accy = fmaf(__uint_as_float(w0 & 0xFFFF0000u), g0, accy);
    }
  }

  float inv = 1.0f / (dsum + 1e-16f);
  accx *= inv;
  accy *= inv;
  float2 sk = *(const float2*)&S[(size_t)n * 128 + lane * 2];
  if (LAYER == 1) {
    float2 b = *(const float2*)&bias[lane * 2];
    float zx = fmaxf(accx + sk.x + b.x, 0.f);
    float zy = fmaxf(accy + sk.y + b.y, 0.f);
    *(float2*)&Out[(size_t)n * 128 + lane * 2] = make_float2(zx, zy);
  } else {
    float zx = accx + sk.x;
    float zy = accy + sk.y;
    float ox = __shfl(zx, lane + 32, 64);
    float oy = __shfl(zy, lane + 32, 64);
    if (lane < 32) {
      float2 b = *(const float2*)&bias[lane * 2];
      float rx = 0.5f * (zx + ox) + b.x;
      float ry = 0.5f * (zy + oy) + b.y;
      *(float2*)&Out[(size_t)n * 64 + lane * 2] = make_float2(rx, ry);
    }
  }
}

// ---------------------------------------------------------------------------
extern "C" void kernel_launch(void* const* d_in, const int* in_sizes, int n_in,
                              void* d_out, int out_size, void* d_ws,
                              size_t ws_size, hipStream_t stream) {
  const float* x = (const float*)d_in[0];
  const int* ei = (const int*)d_in[1];
  const float* W0 = (const float*)d_in[2];
  const float* a_src0 = (const float*)d_in[3];
  const float* a_trg0 = (const float*)d_in[4];
  const float* Wsk0 = (const float*)d_in[5];
  const float* b0 = (const float*)d_in[6];
  const float* W2 = (const float*)d_in[7];
  const float* a_src2 = (const float*)d_in[8];
  const float* a_trg2 = (const float*)d_in[9];
  const float* Wsk2 = (const float*)d_in[10];
  const float* b2 = (const float*)d_in[11];

  const int FIN = 256;
  const int N = in_sizes[0] / FIN;
  const int E = in_sizes[1] / 2;
  const int* src = ei;
  const int* trg = ei + E;

  char* base = (char*)d_ws;
  size_t off = 0;
  auto alloc = [&](size_t bytes) -> void* {
    void* p = base + off;
    off += (bytes + 255) & ~(size_t)255;
    return p;
  };
  float* S = (float*)alloc((size_t)N * 128 * sizeof(float));
  unsigned* PH = (unsigned*)alloc((size_t)N * 64 * sizeof(unsigned));
  int* SS = (int*)alloc((size_t)E * sizeof(int));
  float* ssrc = (float*)alloc((size_t)N * 2 * sizeof(float));
  float* strg = (float*)alloc((size_t)N * 2 * sizeof(float));
  int* rowptr = (int*)alloc((size_t)(N + 1) * sizeof(int));
  int* cursor = (int*)alloc((size_t)N * sizeof(int));
  int* tsum = (int*)alloc((size_t)SCAN_BLOCKS * 256 * sizeof(int));
  int* deg = (int*)alloc((size_t)N * sizeof(int));
  unsigned* WtP0 = (unsigned*)alloc((size_t)128 * 256 * 2);  // bf16
  unsigned* WtS0 = (unsigned*)alloc((size_t)128 * 256 * 2);
  unsigned* WtP2 = (unsigned*)alloc((size_t)128 * 128 * 2);
  unsigned* WtS2 = (unsigned*)alloc((size_t)128 * 128 * 2);

  hipMemsetAsync(deg, 0, (size_t)N * sizeof(int), stream);

  dim3 blk(256);
  int gemmBlocks = (N + 63) / 64;
  int edgeBlocks = (E + 255) / 256;
  int nodeBlocks = (N + 3) / 4;

  // ---- weight prep (bf16, transposed) ----
  wconv<<<16, blk, 0, stream>>>(W0, WtP0, 256);
  wconv<<<16, blk, 0, stream>>>(Wsk0, WtS0, 256);
  wconv<<<8, blk, 0, stream>>>(W2, WtP2, 128);
  wconv<<<8, blk, 0, stream>>>(Wsk2, WtS2, 128);

  // ---- CSR build ----
  deg_count<<<edgeBlocks, blk, 0, stream>>>(trg, deg, E);
  scan_part<<<SCAN_BLOCKS, blk, 0, stream>>>(deg, tsum, N);
  scan_mid<<<1, blk, 0, stream>>>(tsum);
  scan_out<<<SCAN_BLOCKS, blk, 0, stream>>>(deg, tsum, rowptr, cursor, N, E);
  fill_csr<<<edgeBlocks, blk, 0, stream>>>(src, trg, cursor, SS, E);

  // ---- layer 1 ----
  gemm_mfma<1><<<gemmBlocks, blk, 0, stream>>>(x, WtP0, nullptr, PH, a_src0,
                                               a_trg0, ssrc, strg, N, FIN);
  gemm_mfma<0><<<gemmBlocks, blk, 0, stream>>>(x, WtS0, S, nullptr, nullptr,
                                               nullptr, nullptr, nullptr, N,
                                               FIN);
  aggregate<1><<<nodeBlocks, blk, 0, stream>>>(rowptr, SS, (const float2*)ssrc,
                                               (const float2*)strg, PH, S, b0,
                                               S, N);
  // ---- layer 2 (h lives in S) ----
  gemm_mfma<1><<<gemmBlocks, blk, 0, stream>>>(S, WtP2, nullptr, PH, a_src2,
                                               a_trg2, ssrc, strg, N, 128);
  gemm_mfma<0><<<gemmBlocks, blk, 0, stream>>>(S, WtS2, S, nullptr, nullptr,
                                               nullptr, nullptr, nullptr, N,
                                               128);  // in place
  aggregate<2><<<nodeBlocks, blk, 0, stream>>>(rowptr, SS, (const float2*)ssrc,
                                               (const float2*)strg, PH, S, b2,
                                               (float*)d_out, N);
}

// Round 7
// 197.715 us; speedup vs baseline: 5.3546x; 1.3557x over previous
//
#include <hip/hip_runtime.h>

#define NEG_SLOPE 0.2f
#define CBSH 7            // 128 nodes per coarse bucket
#define MAXNC 512         // max buckets (N <= 65536)

typedef __attribute__((ext_vector_type(8))) short short8;
typedef __attribute__((ext_vector_type(4))) float f32x4;

__device__ __forceinline__ unsigned short f2bf(float f) {
  unsigned u = __float_as_uint(f);
  unsigned r = (u + 0x7FFFu + ((u >> 16) & 1u)) >> 16;
  return (unsigned short)r;
}
__device__ __forceinline__ unsigned pack_bf16(float lo, float hi) {
  return (unsigned)f2bf(lo) | ((unsigned)f2bf(hi) << 16);
}

// ---------------------------------------------------------------------------
// W[K][128] fp32 -> Wt[128][K] bf16 (transpose+convert).
// ---------------------------------------------------------------------------
__global__ __launch_bounds__(256) void wconv(const float* __restrict__ W,
                                             unsigned* __restrict__ Wt, int K) {
  int per = K >> 3;
  int t = blockIdx.x * 256 + threadIdx.x;
  if (t >= 128 * per) return;
  int col = t / per;
  int kc = (t - col * per) << 3;
  float w[8];
#pragma unroll
  for (int j = 0; j < 8; ++j) w[j] = W[(size_t)(kc + j) * 128 + col];
  uint4 o = make_uint4(pack_bf16(w[0], w[1]), pack_bf16(w[2], w[3]),
                       pack_bf16(w[4], w[5]), pack_bf16(w[6], w[7]));
  *(uint4*)&Wt[((size_t)col * K + kc) >> 1] = o;
}

// ---------------------------------------------------------------------------
// CSR build, bucket counting-sort (write-combining friendly):
// ccount -> cscan -> cscatter (block-local sort + burst writes) -> bfill.
// ---------------------------------------------------------------------------
__global__ __launch_bounds__(256) void ccount(const int* __restrict__ trg,
                                              int* __restrict__ bcnt, int E,
                                              int NC) {
  __shared__ int hist[MAXNC];
  int tid = threadIdx.x;
  for (int i = tid; i < NC; i += 256) hist[i] = 0;
  __syncthreads();
  for (int e = blockIdx.x * 256 + tid; e < E; e += gridDim.x * 256)
    atomicAdd(&hist[trg[e] >> CBSH], 1);
  __syncthreads();
  for (int i = tid; i < NC; i += 256)
    if (hist[i]) atomicAdd(&bcnt[i], hist[i]);
}

__global__ __launch_bounds__(256) void cscan(const int* __restrict__ bcnt,
                                             int* __restrict__ cbase,
                                             int* __restrict__ gcur, int NC) {
  __shared__ int s[MAXNC + 1];
  int tid = threadIdx.x;
  for (int i = tid; i < NC; i += 256) s[i] = bcnt[i];
  __syncthreads();
  if (tid == 0) {
    int run = 0;
    for (int i = 0; i < NC; ++i) {
      int v = s[i];
      s[i] = run;
      run += v;
    }
    s[NC] = run;
  }
  __syncthreads();
  for (int i = tid; i <= NC; i += 256) cbase[i] = s[i];
  for (int i = tid; i < NC; i += 256) gcur[i] = s[i];
}

// Block-local counting sort of a 4096-edge chunk; per-bucket runs burst-
// written to globally reserved contiguous ranges (single-block line owner).
__global__ __launch_bounds__(256) void cscatter(const int* __restrict__ src,
                                                const int* __restrict__ trg,
                                                int* __restrict__ gcur,
                                                unsigned* __restrict__ EB,
                                                int E, int NC) {
  __shared__ int hist[MAXNC];   // counts, then exclusive scan (lbase)
  __shared__ int gb[MAXNC];     // global base for this block's runs
  __shared__ int lcur[MAXNC];   // placement cursors
  __shared__ unsigned lbuf[4096];
  __shared__ unsigned short cb16[4096];
  int tid = threadIdx.x;
  int e0 = blockIdx.x * 4096;
  int cnt = E - e0;
  if (cnt > 4096) cnt = 4096;
  for (int i = tid; i < NC; i += 256) hist[i] = 0;
  __syncthreads();
  unsigned pk[16];
  unsigned short cbr[16];
  int mine = 0;
#pragma unroll
  for (int j = 0; j < 16; ++j) {
    int i = tid + j * 256;
    if (i < cnt) {
      int e = e0 + i;
      int s = src[e];
      int t = trg[e];
      int cb = t >> CBSH;
      pk[j] = ((unsigned)s << CBSH) | (unsigned)(t & ((1 << CBSH) - 1));
      cbr[j] = (unsigned short)cb;
      atomicAdd(&hist[cb], 1);
      mine = j + 1;
    }
  }
  __syncthreads();
  for (int i = tid; i < NC; i += 256)
    gb[i] = hist[i] ? atomicAdd(&gcur[i], hist[i]) : 0;
  __syncthreads();
  if (tid == 0) {
    int run = 0;
    for (int i = 0; i < NC; ++i) {
      int v = hist[i];
      hist[i] = run;
      run += v;
    }
  }
  __syncthreads();
  for (int i = tid; i < NC; i += 256) lcur[i] = hist[i];
  __syncthreads();
  for (int j = 0; j < mine; ++j) {
    int p = atomicAdd(&lcur[cbr[j]], 1);
    lbuf[p] = pk[j];
    cb16[p] = cbr[j];
  }
  __syncthreads();
  for (int i = tid; i < cnt; i += 256) {
    int cb = cb16[i];
    EB[gb[cb] + (i - hist[cb])] = lbuf[i];
  }
}

// One block per bucket: per-node degrees -> rowptr, then in-region scatter.
__global__ __launch_bounds__(256) void bfill(const unsigned* __restrict__ EB,
                                             const int* __restrict__ cbase,
                                             int* __restrict__ rowptr,
                                             int* __restrict__ SS, int N,
                                             int E) {
  __shared__ int deg[128], lofs[128], cur[128];
  int cb = blockIdx.x;
  int b0 = cbase[cb];
  int b1 = cbase[cb + 1];
  int n0 = cb << CBSH;
  int tid = threadIdx.x;
  if (tid < 128) deg[tid] = 0;
  __syncthreads();
  for (int i = b0 + tid; i < b1; i += 256)
    atomicAdd(&deg[EB[i] & ((1 << CBSH) - 1)], 1);
  __syncthreads();
  if (tid == 0) {
    int run = b0;
    for (int l = 0; l < 128; ++l) {
      lofs[l] = run;
      run += deg[l];
    }
  }
  __syncthreads();
  if (tid < 128) {
    cur[tid] = lofs[tid];
    int n = n0 + tid;
    if (n < N) rowptr[n] = lofs[tid];
  }
  if (cb == 0 && tid == 0) rowptr[N] = E;
  __syncthreads();
  for (int i = b0 + tid; i < b1; i += 256) {
    unsigned pk = EB[i];
    int pos = atomicAdd(&cur[pk & ((1 << CBSH) - 1)], 1);
    SS[pos] = (int)(pk >> CBSH);
  }
}

// ---------------------------------------------------------------------------
// Fused dual bf16-MFMA GEMM: A[MxK] x {BtP, BtS} (both [128][K] bf16).
// Proj output -> PH (packed bf16) + fused attention scores ssrc/strg.
// Skip output -> C fp32 (in-place C==A safe: stores after full K loop).
// mfma_f32_16x16x32_bf16: A row=lane&15,k=(lane>>4)*8+i; B col=lane&15;
// D col=lane&15, row=(lane>>4)*4+reg.
// ---------------------------------------------------------------------------
__global__ __launch_bounds__(256) void gemm_dual(
    const float* __restrict__ A, const unsigned* __restrict__ BtP,
    const unsigned* __restrict__ BtS, float* __restrict__ C,
    unsigned* __restrict__ PH, const float* __restrict__ a_src,
    const float* __restrict__ a_trg, float* __restrict__ ssrc,
    float* __restrict__ strg, int M, int K) {
  __shared__ float Cs[64][132];  // 33792 B; staging aliases it
  unsigned short* lds = (unsigned short*)&Cs[0][0];
  unsigned short(*As)[40] = (unsigned short(*)[40])lds;                    // 5120
  unsigned short(*BsP)[40] = (unsigned short(*)[40])(lds + 64 * 40);       // 10240
  unsigned short(*BsS)[40] = (unsigned short(*)[40])(lds + 64 * 40 + 128 * 40);

  const int tid = threadIdx.x;
  const int lane = tid & 63;
  const int w = tid >> 6;
  const int row0 = blockIdx.x * 64;

  f32x4 accP[8], accS[8];
#pragma unroll
  for (int c = 0; c < 8; ++c) {
    accP[c] = (f32x4)0.f;
    accS[c] = (f32x4)0.f;
  }

  const int arow = tid >> 2;
  const int akq = (tid & 3) << 3;
  const int bcol = tid >> 1;
  const int bh = (tid & 1) << 4;

  for (int k0 = 0; k0 < K; k0 += 32) {
    {
      int gr = row0 + arow;
      float4 v0 = make_float4(0.f, 0.f, 0.f, 0.f), v1 = v0;
      if (gr < M) {
        v0 = *(const float4*)&A[(size_t)gr * K + k0 + akq];
        v1 = *(const float4*)&A[(size_t)gr * K + k0 + akq + 4];
      }
      uint4 p = make_uint4(pack_bf16(v0.x, v0.y), pack_bf16(v0.z, v0.w),
                           pack_bf16(v1.x, v1.y), pack_bf16(v1.z, v1.w));
      *(uint4*)&As[arow][akq] = p;
    }
    {
      size_t base = ((size_t)bcol * K + k0 + bh) >> 1;
      uint4 p0 = *(const uint4*)&BtP[base];
      uint4 p1 = *(const uint4*)&BtP[base + 4];
      *(uint4*)&BsP[bcol][bh] = p0;
      *(uint4*)&BsP[bcol][bh + 8] = p1;
      uint4 s0 = *(const uint4*)&BtS[base];
      uint4 s1 = *(const uint4*)&BtS[base + 4];
      *(uint4*)&BsS[bcol][bh] = s0;
      *(uint4*)&BsS[bcol][bh + 8] = s1;
    }
    __syncthreads();
    short8 af = *(const short8*)&As[16 * w + (lane & 15)][(lane >> 4) << 3];
#pragma unroll
    for (int c = 0; c < 8; ++c) {
      short8 bp = *(const short8*)&BsP[16 * c + (lane & 15)][(lane >> 4) << 3];
      accP[c] = __builtin_amdgcn_mfma_f32_16x16x32_bf16(af, bp, accP[c], 0, 0, 0);
      short8 bs = *(const short8*)&BsS[16 * c + (lane & 15)][(lane >> 4) << 3];
      accS[c] = __builtin_amdgcn_mfma_f32_16x16x32_bf16(af, bs, accS[c], 0, 0, 0);
    }
    __syncthreads();
  }

  const int hrow = lane >> 5;
  const int c32 = lane & 31;

  // ---- proj epilogue: PH + scores ----
#pragma unroll
  for (int c = 0; c < 8; ++c)
#pragma unroll
    for (int r = 0; r < 4; ++r)
      Cs[16 * w + ((lane >> 4) << 2) + r][16 * c + (lane & 15)] = accP[c][r];
  __syncthreads();
#pragma unroll
  for (int i = 0; i < 8; ++i) {
    int lr = 16 * w + 2 * i + hrow;
    int gr = row0 + lr;
    if (gr < M) {
      float4 v = *(const float4*)&Cs[lr][c32 * 4];
      *(uint2*)&PH[(size_t)gr * 64 + c32 * 2] =
          make_uint2(pack_bf16(v.x, v.y), pack_bf16(v.z, v.w));
    }
  }
  {
    int srow = tid >> 2;
    int q = tid & 3;
    int gr = row0 + srow;
    float ds = 0.f, dt = 0.f;
#pragma unroll
    for (int j = 0; j < 8; ++j) {
      int col = q * 32 + j * 4;
      float4 v = *(const float4*)&Cs[srow][col];
      float4 asv = *(const float4*)&a_src[col];
      float4 atv = *(const float4*)&a_trg[col];
      ds += v.x * asv.x + v.y * asv.y + v.z * asv.z + v.w * asv.w;
      dt += v.x * atv.x + v.y * atv.y + v.z * atv.z + v.w * atv.w;
    }
    ds += __shfl_xor(ds, 1, 64);
    dt += __shfl_xor(dt, 1, 64);
    if (gr < M && (q & 1) == 0) {
      int h = q >> 1;
      ssrc[gr * 2 + h] = ds;
      strg[gr * 2 + h] = dt;
    }
  }
  __syncthreads();

  // ---- skip epilogue: C fp32 ----
#pragma unroll
  for (int c = 0; c < 8; ++c)
#pragma unroll
    for (int r = 0; r < 4; ++r)
      Cs[16 * w + ((lane >> 4) << 2) + r][16 * c + (lane & 15)] = accS[c][r];
  __syncthreads();
#pragma unroll
  for (int i = 0; i < 8; ++i) {
    int lr = 16 * w + 2 * i + hrow;
    int gr = row0 + lr;
    if (gr < M) {
      float4 v = *(const float4*)&Cs[lr][c32 * 4];
      *(float4*)&C[(size_t)gr * 128 + c32 * 4] = v;
    }
  }
}

// ---------------------------------------------------------------------------
// Fused aggregation (unchanged): one wave per node; weights recomputed on the
// fly; bf16 messages from PH; readlane-broadcast indices; 4 edges in flight.
// ---------------------------------------------------------------------------
template <int LAYER>
__global__ __launch_bounds__(256) void aggregate(
    const int* __restrict__ rowptr, const int* __restrict__ SS,
    const float2* __restrict__ ssrc, const float2* __restrict__ strg,
    const unsigned* __restrict__ PH, const float* __restrict__ S,
    const float* __restrict__ bias, float* __restrict__ Out, int Nn) {
  int wid = (int)((blockIdx.x * blockDim.x + threadIdx.x) >> 6);
  int lane = threadIdx.x & 63;
  if (wid >= Nn) return;
  int n = wid;
  bool hi = lane >= 32;
  float2 st = strg[n];
  float et = hi ? st.y : st.x;
  int beg = rowptr[n];
  int end = rowptr[n + 1];
  float accx = 0.f, accy = 0.f, dsum = 0.f;

  for (int base = beg; base < end; base += 64) {
    int cnt = end - base;
    if (cnt > 64) cnt = 64;
    int idx = base + lane;
    int sv = (idx < end) ? SS[idx] : 0;
    int j = 0;
    for (; j + 4 <= cnt; j += 4) {
      int s0 = __builtin_amdgcn_readlane(sv, j + 0);
      int s1 = __builtin_amdgcn_readlane(sv, j + 1);
      int s2 = __builtin_amdgcn_readlane(sv, j + 2);
      int s3 = __builtin_amdgcn_readlane(sv, j + 3);
      unsigned w0 = PH[(size_t)s0 * 64 + lane];
      unsigned w1 = PH[(size_t)s1 * 64 + lane];
      unsigned w2 = PH[(size_t)s2 * 64 + lane];
      unsigned w3 = PH[(size_t)s3 * 64 + lane];
      float2 e0 = ssrc[s0];
      float2 e1 = ssrc[s1];
      float2 e2 = ssrc[s2];
      float2 e3 = ssrc[s3];
      float z0 = (hi ? e0.y : e0.x) + et;
      float z1 = (hi ? e1.y : e1.x) + et;
      float z2 = (hi ? e2.y : e2.x) + et;
      float z3 = (hi ? e3.y : e3.x) + et;
      z0 = (z0 >= 0.f) ? z0 : NEG_SLOPE * z0;
      z1 = (z1 >= 0.f) ? z1 : NEG_SLOPE * z1;
      z2 = (z2 >= 0.f) ? z2 : NEG_SLOPE * z2;
      z3 = (z3 >= 0.f) ? z3 : NEG_SLOPE * z3;
      float g0 = __expf(z0), g1 = __expf(z1), g2 = __expf(z2), g3 = __expf(z3);
      dsum += (g0 + g1) + (g2 + g3);
      accx = fmaf(__uint_as_float(w0 << 16), g0, accx);
      accy = fmaf(__uint_as_float(w0 & 0xFFFF0000u), g0, accy);
      accx = fmaf(__uint_as_float(w1 << 16), g1, accx);
      accy = fmaf(__uint_as_float(w1 & 0xFFFF0000u), g1, accy);
      accx = fmaf(__uint_as_float(w2 << 16), g2, accx);
      accy = fmaf(__uint_as_float(w2 & 0xFFFF0000u), g2, accy);
      accx = fmaf(__uint_as_float(w3 << 16), g3, accx);
      accy = fmaf(__uint_as_float(w3 & 0xFFFF0000u), g3, accy);
    }
    for (; j < cnt; ++j) {
      int s0 = __builtin_amdgcn_readlane(sv, j);
      unsigned w0 = PH[(size_t)s0 * 64 + lane];
      float2 e0 = ssrc[s0];
      float z0 = (hi ? e0.y : e0.x) + et;
      z0 = (z0 >= 0.f) ? z0 : NEG_SLOPE * z0;
      float g0 = __expf(z0);
      dsum += g0;
      accx = fmaf(__uint_as_float(w0 << 16), g0, accx);
      accy = fmaf(__uint_as_float(w0 & 0xFFFF0000u), g0, accy);
    }
  }

  float inv = 1.0f / (dsum + 1e-16f);
  accx *= inv;
  accy *= inv;
  float2 sk = *(const float2*)&S[(size_t)n * 128 + lane * 2];
  if (LAYER == 1) {
    float2 b = *(const float2*)&bias[lane * 2];
    float zx = fmaxf(accx + sk.x + b.x, 0.f);
    float zy = fmaxf(accy + sk.y + b.y, 0.f);
    *(float2*)&Out[(size_t)n * 128 + lane * 2] = make_float2(zx, zy);
  } else {
    float zx = accx + sk.x;
    float zy = accy + sk.y;
    float ox = __shfl(zx, lane + 32, 64);
    float oy = __shfl(zy, lane + 32, 64);
    if (lane < 32) {
      float2 b = *(const float2*)&bias[lane * 2];
      float rx = 0.5f * (zx + ox) + b.x;
      float ry = 0.5f * (zy + oy) + b.y;
      *(float2*)&Out[(size_t)n * 64 + lane * 2] = make_float2(rx, ry);
    }
  }
}

// ---------------------------------------------------------------------------
extern "C" void kernel_launch(void* const* d_in, const int* in_sizes, int n_in,
                              void* d_out, int out_size, void* d_ws,
                              size_t ws_size, hipStream_t stream) {
  const float* x = (const float*)d_in[0];
  const int* ei = (const int*)d_in[1];
  const float* W0 = (const float*)d_in[2];
  const float* a_src0 = (const float*)d_in[3];
  const float* a_trg0 = (const float*)d_in[4];
  const float* Wsk0 = (const float*)d_in[5];
  const float* b0 = (const float*)d_in[6];
  const float* W2 = (const float*)d_in[7];
  const float* a_src2 = (const float*)d_in[8];
  const float* a_trg2 = (const float*)d_in[9];
  const float* Wsk2 = (const float*)d_in[10];
  const float* b2 = (const float*)d_in[11];

  const int FIN = 256;
  const int N = in_sizes[0] / FIN;
  const int E = in_sizes[1] / 2;
  const int* src = ei;
  const int* trg = ei + E;
  const int NC = (N + (1 << CBSH) - 1) >> CBSH;

  char* base = (char*)d_ws;
  size_t off = 0;
  auto alloc = [&](size_t bytes) -> void* {
    void* p = base + off;
    off += (bytes + 255) & ~(size_t)255;
    return p;
  };
  float* S = (float*)alloc((size_t)N * 128 * sizeof(float));
  unsigned* PH = (unsigned*)alloc((size_t)N * 64 * sizeof(unsigned));
  int* SS = (int*)alloc((size_t)E * sizeof(int));
  unsigned* EB = (unsigned*)alloc((size_t)E * sizeof(unsigned));
  float* ssrc = (float*)alloc((size_t)N * 2 * sizeof(float));
  float* strg = (float*)alloc((size_t)N * 2 * sizeof(float));
  int* rowptr = (int*)alloc((size_t)(N + 1) * sizeof(int));
  int* bcnt = (int*)alloc((size_t)MAXNC * sizeof(int));
  int* cbase = (int*)alloc((size_t)(MAXNC + 1) * sizeof(int));
  int* gcur = (int*)alloc((size_t)MAXNC * sizeof(int));
  unsigned* WtP0 = (unsigned*)alloc((size_t)128 * 256 * 2);
  unsigned* WtS0 = (unsigned*)alloc((size_t)128 * 256 * 2);
  unsigned* WtP2 = (unsigned*)alloc((size_t)128 * 128 * 2);
  unsigned* WtS2 = (unsigned*)alloc((size_t)128 * 128 * 2);

  hipMemsetAsync(bcnt, 0, (size_t)MAXNC * sizeof(int), stream);

  dim3 blk(256);
  int gemmBlocks = (N + 63) / 64;
  int nodeBlocks = (N + 3) / 4;
  int chunkBlocks = (E + 4095) / 4096;

  // ---- weight prep ----
  wconv<<<16, blk, 0, stream>>>(W0, WtP0, 256);
  wconv<<<16, blk, 0, stream>>>(Wsk0, WtS0, 256);
  wconv<<<8, blk, 0, stream>>>(W2, WtP2, 128);
  wconv<<<8, blk, 0, stream>>>(Wsk2, WtS2, 128);

  // ---- CSR build (bucket counting sort) ----
  ccount<<<256, blk, 0, stream>>>(trg, bcnt, E, NC);
  cscan<<<1, blk, 0, stream>>>(bcnt, cbase, gcur, NC);
  cscatter<<<chunkBlocks, blk, 0, stream>>>(src, trg, gcur, EB, E, NC);
  bfill<<<NC, blk, 0, stream>>>(EB, cbase, rowptr, SS, N, E);

  // ---- layer 1 ----
  gemm_dual<<<gemmBlocks, blk, 0, stream>>>(x, WtP0, WtS0, S, PH, a_src0,
                                            a_trg0, ssrc, strg, N, FIN);
  aggregate<1><<<nodeBlocks, blk, 0, stream>>>(rowptr, SS, (const float2*)ssrc,
                                               (const float2*)strg, PH, S, b0,
                                               S, N);
  // ---- layer 2 (h lives in S) ----
  gemm_dual<<<gemmBlocks, blk, 0, stream>>>(S, WtP2, WtS2, S, PH, a_src2,
                                            a_trg2, ssrc, strg, N, 128);
  aggregate<2><<<nodeBlocks, blk, 0, stream>>>(rowptr, SS, (const float2*)ssrc,
                                               (const float2*)strg, PH, S, b2,
                                               (float*)d_out, N);
}

// Round 8
// 195.228 us; speedup vs baseline: 5.4228x; 1.0127x over previous
//
#include <hip/hip_runtime.h>

#define NEG_SLOPE 0.2f
#define CBSH 7            // 128 nodes per coarse bucket
#define MAXNC 512         // max buckets (N <= 65536)

typedef __attribute__((ext_vector_type(8))) short short8;
typedef __attribute__((ext_vector_type(4))) float f32x4;

__device__ __forceinline__ unsigned short f2bf(float f) {
  unsigned u = __float_as_uint(f);
  unsigned r = (u + 0x7FFFu + ((u >> 16) & 1u)) >> 16;
  return (unsigned short)r;
}
__device__ __forceinline__ unsigned pack_bf16(float lo, float hi) {
  return (unsigned)f2bf(lo) | ((unsigned)f2bf(hi) << 16);
}
__device__ __forceinline__ void gload_lds16(const void* g, void* l) {
  __builtin_amdgcn_global_load_lds(
      (const __attribute__((address_space(1))) unsigned*)g,
      (__attribute__((address_space(3))) unsigned*)l, 16, 0, 0);
}

// ---------------------------------------------------------------------------
// W[K][128] fp32 -> Wt[128][K] bf16 (transpose+convert).
// ---------------------------------------------------------------------------
__global__ __launch_bounds__(256) void wconv(const float* __restrict__ W,
                                             unsigned* __restrict__ Wt, int K) {
  int per = K >> 3;
  int t = blockIdx.x * 256 + threadIdx.x;
  if (t >= 128 * per) return;
  int col = t / per;
  int kc = (t - col * per) << 3;
  float w[8];
#pragma unroll
  for (int j = 0; j < 8; ++j) w[j] = W[(size_t)(kc + j) * 128 + col];
  uint4 o = make_uint4(pack_bf16(w[0], w[1]), pack_bf16(w[2], w[3]),
                       pack_bf16(w[4], w[5]), pack_bf16(w[6], w[7]));
  *(uint4*)&Wt[((size_t)col * K + kc) >> 1] = o;
}

// ---------------------------------------------------------------------------
// CSR build, bucket counting-sort (write-combining friendly).
// ---------------------------------------------------------------------------
__global__ __launch_bounds__(256) void ccount(const int* __restrict__ trg,
                                              int* __restrict__ bcnt, int E,
                                              int NC) {
  __shared__ int hist[MAXNC];
  int tid = threadIdx.x;
  for (int i = tid; i < NC; i += 256) hist[i] = 0;
  __syncthreads();
  for (int e = blockIdx.x * 256 + tid; e < E; e += gridDim.x * 256)
    atomicAdd(&hist[trg[e] >> CBSH], 1);
  __syncthreads();
  for (int i = tid; i < NC; i += 256)
    if (hist[i]) atomicAdd(&bcnt[i], hist[i]);
}

__global__ __launch_bounds__(256) void cscan(const int* __restrict__ bcnt,
                                             int* __restrict__ cbase,
                                             int* __restrict__ gcur, int NC) {
  __shared__ int s[MAXNC + 1];
  int tid = threadIdx.x;
  for (int i = tid; i < NC; i += 256) s[i] = bcnt[i];
  __syncthreads();
  if (tid == 0) {
    int run = 0;
    for (int i = 0; i < NC; ++i) {
      int v = s[i];
      s[i] = run;
      run += v;
    }
    s[NC] = run;
  }
  __syncthreads();
  for (int i = tid; i <= NC; i += 256) cbase[i] = s[i];
  for (int i = tid; i < NC; i += 256) gcur[i] = s[i];
}

__global__ __launch_bounds__(256) void cscatter(const int* __restrict__ src,
                                                const int* __restrict__ trg,
                                                int* __restrict__ gcur,
                                                unsigned* __restrict__ EB,
                                                int E, int NC) {
  __shared__ int hist[MAXNC];
  __shared__ int gb[MAXNC];
  __shared__ int lcur[MAXNC];
  __shared__ unsigned lbuf[4096];
  __shared__ unsigned short cb16[4096];
  int tid = threadIdx.x;
  int e0 = blockIdx.x * 4096;
  int cnt = E - e0;
  if (cnt > 4096) cnt = 4096;
  for (int i = tid; i < NC; i += 256) hist[i] = 0;
  __syncthreads();
  unsigned pk[16];
  unsigned short cbr[16];
  int mine = 0;
#pragma unroll
  for (int j = 0; j < 16; ++j) {
    int i = tid + j * 256;
    if (i < cnt) {
      int e = e0 + i;
      int s = src[e];
      int t = trg[e];
      int cb = t >> CBSH;
      pk[j] = ((unsigned)s << CBSH) | (unsigned)(t & ((1 << CBSH) - 1));
      cbr[j] = (unsigned short)cb;
      atomicAdd(&hist[cb], 1);
      mine = j + 1;
    }
  }
  __syncthreads();
  for (int i = tid; i < NC; i += 256)
    gb[i] = hist[i] ? atomicAdd(&gcur[i], hist[i]) : 0;
  __syncthreads();
  if (tid == 0) {
    int run = 0;
    for (int i = 0; i < NC; ++i) {
      int v = hist[i];
      hist[i] = run;
      run += v;
    }
  }
  __syncthreads();
  for (int i = tid; i < NC; i += 256) lcur[i] = hist[i];
  __syncthreads();
  for (int j = 0; j < mine; ++j) {
    int p = atomicAdd(&lcur[cbr[j]], 1);
    lbuf[p] = pk[j];
    cb16[p] = cbr[j];
  }
  __syncthreads();
  for (int i = tid; i < cnt; i += 256) {
    int cb = cb16[i];
    EB[gb[cb] + (i - hist[cb])] = lbuf[i];
  }
}

__global__ __launch_bounds__(256) void bfill(const unsigned* __restrict__ EB,
                                             const int* __restrict__ cbase,
                                             int* __restrict__ rowptr,
                                             int* __restrict__ SS, int N,
                                             int E) {
  __shared__ int deg[128], lofs[128], cur[128];
  int cb = blockIdx.x;
  int b0 = cbase[cb];
  int b1 = cbase[cb + 1];
  int n0 = cb << CBSH;
  int tid = threadIdx.x;
  if (tid < 128) deg[tid] = 0;
  __syncthreads();
  for (int i = b0 + tid; i < b1; i += 256)
    atomicAdd(&deg[EB[i] & ((1 << CBSH) - 1)], 1);
  __syncthreads();
  if (tid == 0) {
    int run = b0;
    for (int l = 0; l < 128; ++l) {
      lofs[l] = run;
      run += deg[l];
    }
  }
  __syncthreads();
  if (tid < 128) {
    cur[tid] = lofs[tid];
    int n = n0 + tid;
    if (n < N) rowptr[n] = lofs[tid];
  }
  if (cb == 0 && tid == 0) rowptr[N] = E;
  __syncthreads();
  for (int i = b0 + tid; i < b1; i += 256) {
    unsigned pk = EB[i];
    int pos = atomicAdd(&cur[pk & ((1 << CBSH) - 1)], 1);
    SS[pos] = (int)(pk >> CBSH);
  }
}

// ---------------------------------------------------------------------------
// Fused dual bf16-MFMA GEMM, 2-phase pipelined, fragment-ordered LDS.
// LDS stage buffer (per buf, 20480 B): A @ +0 (4KB), BP @ +4096, BS @ +12288.
// Fragment-ordered: chunk16(frag, lane) at frag*1024 + lane*16 -> every MFMA
// operand is one conflict-free ds_read_b128 (64 lanes span 1KB contiguous).
// B staged via global_load_lds (dest linear in lane; the fragment permutation
// is applied on the per-lane GLOBAL source address). A staged via reg+pack.
// Per K-step: issue stage(t+1) -> MFMA(t) -> write A(t+1) -> one barrier.
// Epilogue (Cs[64][132] aliased over the stage buffers): PH + fused scores,
// then C fp32. In-place C==A safe (stores after full K loop).
// ---------------------------------------------------------------------------
__global__ __launch_bounds__(256) void gemm_dual(
    const float* __restrict__ A, const unsigned* __restrict__ BtP,
    const unsigned* __restrict__ BtS, float* __restrict__ C,
    unsigned* __restrict__ PH, const float* __restrict__ a_src,
    const float* __restrict__ a_trg, float* __restrict__ ssrc,
    float* __restrict__ strg, int M, int K) {
  __shared__ __align__(16) char ldsraw[40960];
  float(*Cs)[132] = (float(*)[132])ldsraw;

  const int tid = threadIdx.x;
  const int lane = tid & 63;
  const int w = tid >> 6;
  const int row0 = blockIdx.x * 64;

  f32x4 accP[8], accS[8];
#pragma unroll
  for (int c = 0; c < 8; ++c) {
    accP[c] = (f32x4)0.f;
    accS[c] = (f32x4)0.f;
  }

  // A staging: coalesced global read (4 threads x 32B per row),
  // ds_write_b128 to fragment-ordered chunk.
  const int arow = tid >> 2;
  const int akq = (tid & 3) << 3;
  const int agr = row0 + arow;
  const int abyte =
      ((((arow >> 4) << 6) | ((tid & 3) << 4) | (arow & 15)) << 4);
  // B staging: instr (w,i) covers col-frag c=w*2+i; lane -> col 16c+(lane&15),
  // k-slot lane>>4.
  const unsigned short* BP16 = (const unsigned short*)BtP;
  const unsigned short* BS16 = (const unsigned short*)BtS;
  const int bg = lane >> 4;
  const int br = lane & 15;

  const int nt = K >> 5;

  auto stage_b = [&](int buf, int k0) {
    char* sb = ldsraw + buf * 20480;
#pragma unroll
    for (int i = 0; i < 2; ++i) {
      int c = w * 2 + i;
      size_t eoff = (size_t)(16 * c + br) * K + k0 + 8 * bg;
      gload_lds16(BP16 + eoff, sb + 4096 + c * 1024);
      gload_lds16(BS16 + eoff, sb + 12288 + c * 1024);
    }
  };
  auto load_a = [&](int k0, float4& v0, float4& v1) {
    v0 = make_float4(0.f, 0.f, 0.f, 0.f);
    v1 = v0;
    if (agr < M) {
      v0 = *(const float4*)&A[(size_t)agr * K + k0 + akq];
      v1 = *(const float4*)&A[(size_t)agr * K + k0 + akq + 4];
    }
  };
  auto write_a = [&](int buf, const float4& v0, const float4& v1) {
    uint4 p = make_uint4(pack_bf16(v0.x, v0.y), pack_bf16(v0.z, v0.w),
                         pack_bf16(v1.x, v1.y), pack_bf16(v1.z, v1.w));
    *(uint4*)(ldsraw + buf * 20480 + abyte) = p;
  };

  {
    float4 v0, v1;
    stage_b(0, 0);
    load_a(0, v0, v1);
    write_a(0, v0, v1);
  }
  __syncthreads();

  int cur = 0;
  for (int t = 0; t < nt; ++t) {
    float4 v0, v1;
    const bool pf = (t + 1 < nt);
    if (pf) {
      stage_b(cur ^ 1, (t + 1) << 5);
      load_a((t + 1) << 5, v0, v1);
    }
    const char* sb = ldsraw + cur * 20480;
    short8 af = *(const short8*)(sb + w * 1024 + lane * 16);
#pragma unroll
    for (int c = 0; c < 8; ++c) {
      short8 bp = *(const short8*)(sb + 4096 + c * 1024 + lane * 16);
      accP[c] =
          __builtin_amdgcn_mfma_f32_16x16x32_bf16(af, bp, accP[c], 0, 0, 0);
    }
#pragma unroll
    for (int c = 0; c < 8; ++c) {
      short8 bs = *(const short8*)(sb + 12288 + c * 1024 + lane * 16);
      accS[c] =
          __builtin_amdgcn_mfma_f32_16x16x32_bf16(af, bs, accS[c], 0, 0, 0);
    }
    if (pf) write_a(cur ^ 1, v0, v1);
    __syncthreads();
    cur ^= 1;
  }

  const int hrow = lane >> 5;
  const int c32 = lane & 31;

  // ---- proj epilogue: PH + scores ----
#pragma unroll
  for (int c = 0; c < 8; ++c)
#pragma unroll
    for (int r = 0; r < 4; ++r)
      Cs[16 * w + ((lane >> 4) << 2) + r][16 * c + (lane & 15)] = accP[c][r];
  __syncthreads();
#pragma unroll
  for (int i = 0; i < 8; ++i) {
    int lr = 16 * w + 2 * i + hrow;
    int gr = row0 + lr;
    if (gr < M) {
      float4 v = *(const float4*)&Cs[lr][c32 * 4];
      *(uint2*)&PH[(size_t)gr * 64 + c32 * 2] =
          make_uint2(pack_bf16(v.x, v.y), pack_bf16(v.z, v.w));
    }
  }
  {
    int srow = tid >> 2;
    int q = tid & 3;
    int gr = row0 + srow;
    float ds = 0.f, dt = 0.f;
#pragma unroll
    for (int j = 0; j < 8; ++j) {
      int col = q * 32 + j * 4;
      float4 v = *(const float4*)&Cs[srow][col];
      float4 asv = *(const float4*)&a_src[col];
      float4 atv = *(const float4*)&a_trg[col];
      ds += v.x * asv.x + v.y * asv.y + v.z * asv.z + v.w * asv.w;
      dt += v.x * atv.x + v.y * atv.y + v.z * atv.z + v.w * atv.w;
    }
    ds += __shfl_xor(ds, 1, 64);
    dt += __shfl_xor(dt, 1, 64);
    if (gr < M && (q & 1) == 0) {
      int h = q >> 1;
      ssrc[gr * 2 + h] = ds;
      strg[gr * 2 + h] = dt;
    }
  }
  __syncthreads();

  // ---- skip epilogue: C fp32 ----
#pragma unroll
  for (int c = 0; c < 8; ++c)
#pragma unroll
    for (int r = 0; r < 4; ++r)
      Cs[16 * w + ((lane >> 4) << 2) + r][16 * c + (lane & 15)] = accS[c][r];
  __syncthreads();
#pragma unroll
  for (int i = 0; i < 8; ++i) {
    int lr = 16 * w + 2 * i + hrow;
    int gr = row0 + lr;
    if (gr < M) {
      float4 v = *(const float4*)&Cs[lr][c32 * 4];
      *(float4*)&C[(size_t)gr * 128 + c32 * 4] = v;
    }
  }
}

// ---------------------------------------------------------------------------
// Fused aggregation (unchanged): one wave per node; weights recomputed on the
// fly; bf16 messages from PH; readlane-broadcast indices; 4 edges in flight.
// ---------------------------------------------------------------------------
template <int LAYER>
__global__ __launch_bounds__(256) void aggregate(
    const int* __restrict__ rowptr, const int* __restrict__ SS,
    const float2* __restrict__ ssrc, const float2* __restrict__ strg,
    const unsigned* __restrict__ PH, const float* __restrict__ S,
    const float* __restrict__ bias, float* __restrict__ Out, int Nn) {
  int wid = (int)((blockIdx.x * blockDim.x + threadIdx.x) >> 6);
  int lane = threadIdx.x & 63;
  if (wid >= Nn) return;
  int n = wid;
  bool hi = lane >= 32;
  float2 st = strg[n];
  float et = hi ? st.y : st.x;
  int beg = rowptr[n];
  int end = rowptr[n + 1];
  float accx = 0.f, accy = 0.f, dsum = 0.f;

  for (int base = beg; base < end; base += 64) {
    int cnt = end - base;
    if (cnt > 64) cnt = 64;
    int idx = base + lane;
    int sv = (idx < end) ? SS[idx] : 0;
    int j = 0;
    for (; j + 4 <= cnt; j += 4) {
      int s0 = __builtin_amdgcn_readlane(sv, j + 0);
      int s1 = __builtin_amdgcn_readlane(sv, j + 1);
      int s2 = __builtin_amdgcn_readlane(sv, j + 2);
      int s3 = __builtin_amdgcn_readlane(sv, j + 3);
      unsigned w0 = PH[(size_t)s0 * 64 + lane];
      unsigned w1 = PH[(size_t)s1 * 64 + lane];
      unsigned w2 = PH[(size_t)s2 * 64 + lane];
      unsigned w3 = PH[(size_t)s3 * 64 + lane];
      float2 e0 = ssrc[s0];
      float2 e1 = ssrc[s1];
      float2 e2 = ssrc[s2];
      float2 e3 = ssrc[s3];
      float z0 = (hi ? e0.y : e0.x) + et;
      float z1 = (hi ? e1.y : e1.x) + et;
      float z2 = (hi ? e2.y : e2.x) + et;
      float z3 = (hi ? e3.y : e3.x) + et;
      z0 = (z0 >= 0.f) ? z0 : NEG_SLOPE * z0;
      z1 = (z1 >= 0.f) ? z1 : NEG_SLOPE * z1;
      z2 = (z2 >= 0.f) ? z2 : NEG_SLOPE * z2;
      z3 = (z3 >= 0.f) ? z3 : NEG_SLOPE * z3;
      float g0 = __expf(z0), g1 = __expf(z1), g2 = __expf(z2), g3 = __expf(z3);
      dsum += (g0 + g1) + (g2 + g3);
      accx = fmaf(__uint_as_float(w0 << 16), g0, accx);
      accy = fmaf(__uint_as_float(w0 & 0xFFFF0000u), g0, accy);
      accx = fmaf(__uint_as_float(w1 << 16), g1, accx);
      accy = fmaf(__uint_as_float(w1 & 0xFFFF0000u), g1, accy);
      accx = fmaf(__uint_as_float(w2 << 16), g2, accx);
      accy = fmaf(__uint_as_float(w2 & 0xFFFF0000u), g2, accy);
      accx = fmaf(__uint_as_float(w3 << 16), g3, accx);
      accy = fmaf(__uint_as_float(w3 & 0xFFFF0000u), g3, accy);
    }
    for (; j < cnt; ++j) {
      int s0 = __builtin_amdgcn_readlane(sv, j);
      unsigned w0 = PH[(size_t)s0 * 64 + lane];
      float2 e0 = ssrc[s0];
      float z0 = (hi ? e0.y : e0.x) + et;
      z0 = (z0 >= 0.f) ? z0 : NEG_SLOPE * z0;
      float g0 = __expf(z0);
      dsum += g0;
      accx = fmaf(__uint_as_float(w0 << 16), g0, accx);
      accy = fmaf(__uint_as_float(w0 & 0xFFFF0000u), g0, accy);
    }
  }

  float inv = 1.0f / (dsum + 1e-16f);
  accx *= inv;
  accy *= inv;
  float2 sk = *(const float2*)&S[(size_t)n * 128 + lane * 2];
  if (LAYER == 1) {
    float2 b = *(const float2*)&bias[lane * 2];
    float zx = fmaxf(accx + sk.x + b.x, 0.f);
    float zy = fmaxf(accy + sk.y + b.y, 0.f);
    *(float2*)&Out[(size_t)n * 128 + lane * 2] = make_float2(zx, zy);
  } else {
    float zx = accx + sk.x;
    float zy = accy + sk.y;
    float ox = __shfl(zx, lane + 32, 64);
    float oy = __shfl(zy, lane + 32, 64);
    if (lane < 32) {
      float2 b = *(const float2*)&bias[lane * 2];
      float rx = 0.5f * (zx + ox) + b.x;
      float ry = 0.5f * (zy + oy) + b.y;
      *(float2*)&Out[(size_t)n * 64 + lane * 2] = make_float2(rx, ry);
    }
  }
}

// ---------------------------------------------------------------------------
extern "C" void kernel_launch(void* const* d_in, const int* in_sizes, int n_in,
                              void* d_out, int out_size, void* d_ws,
                              size_t ws_size, hipStream_t stream) {
  const float* x = (const float*)d_in[0];
  const int* ei = (const int*)d_in[1];
  const float* W0 = (const float*)d_in[2];
  const float* a_src0 = (const float*)d_in[3];
  const float* a_trg0 = (const float*)d_in[4];
  const float* Wsk0 = (const float*)d_in[5];
  const float* b0 = (const float*)d_in[6];
  const float* W2 = (const float*)d_in[7];
  const float* a_src2 = (const float*)d_in[8];
  const float* a_trg2 = (const float*)d_in[9];
  const float* Wsk2 = (const float*)d_in[10];
  const float* b2 = (const float*)d_in[11];

  const int FIN = 256;
  const int N = in_sizes[0] / FIN;
  const int E = in_sizes[1] / 2;
  const int* src = ei;
  const int* trg = ei + E;
  const int NC = (N + (1 << CBSH) - 1) >> CBSH;

  char* base = (char*)d_ws;
  size_t off = 0;
  auto alloc = [&](size_t bytes) -> void* {
    void* p = base + off;
    off += (bytes + 255) & ~(size_t)255;
    return p;
  };
  float* S = (float*)alloc((size_t)N * 128 * sizeof(float));
  unsigned* PH = (unsigned*)alloc((size_t)N * 64 * sizeof(unsigned));
  int* SS = (int*)alloc((size_t)E * sizeof(int));
  unsigned* EB = (unsigned*)alloc((size_t)E * sizeof(unsigned));
  float* ssrc = (float*)alloc((size_t)N * 2 * sizeof(float));
  float* strg = (float*)alloc((size_t)N * 2 * sizeof(float));
  int* rowptr = (int*)alloc((size_t)(N + 1) * sizeof(int));
  int* bcnt = (int*)alloc((size_t)MAXNC * sizeof(int));
  int* cbase = (int*)alloc((size_t)(MAXNC + 1) * sizeof(int));
  int* gcur = (int*)alloc((size_t)MAXNC * sizeof(int));
  unsigned* WtP0 = (unsigned*)alloc((size_t)128 * 256 * 2);
  unsigned* WtS0 = (unsigned*)alloc((size_t)128 * 256 * 2);
  unsigned* WtP2 = (unsigned*)alloc((size_t)128 * 128 * 2);
  unsigned* WtS2 = (unsigned*)alloc((size_t)128 * 128 * 2);

  hipMemsetAsync(bcnt, 0, (size_t)MAXNC * sizeof(int), stream);

  dim3 blk(256);
  int gemmBlocks = (N + 63) / 64;
  int nodeBlocks = (N + 3) / 4;
  int chunkBlocks = (E + 4095) / 4096;

  // ---- weight prep ----
  wconv<<<16, blk, 0, stream>>>(W0, WtP0, 256);
  wconv<<<16, blk, 0, stream>>>(Wsk0, WtS0, 256);
  wconv<<<8, blk, 0, stream>>>(W2, WtP2, 128);
  wconv<<<8, blk, 0, stream>>>(Wsk2, WtS2, 128);

  // ---- CSR build (bucket counting sort) ----
  ccount<<<256, blk, 0, stream>>>(trg, bcnt, E, NC);
  cscan<<<1, blk, 0, stream>>>(bcnt, cbase, gcur, NC);
  cscatter<<<chunkBlocks, blk, 0, stream>>>(src, trg, gcur, EB, E, NC);
  bfill<<<NC, blk, 0, stream>>>(EB, cbase, rowptr, SS, N, E);

  // ---- layer 1 ----
  gemm_dual<<<gemmBlocks, blk, 0, stream>>>(x, WtP0, WtS0, S, PH, a_src0,
                                            a_trg0, ssrc, strg, N, FIN);
  aggregate<1><<<nodeBlocks, blk, 0, stream>>>(rowptr, SS, (const float2*)ssrc,
                                               (const float2*)strg, PH, S, b0,
                                               S, N);
  // ---- layer 2 (h lives in S) ----
  gemm_dual<<<gemmBlocks, blk, 0, stream>>>(S, WtP2, WtS2, S, PH, a_src2,
                                            a_trg2, ssrc, strg, N, 128);
  aggregate<2><<<nodeBlocks, blk, 0, stream>>>(rowptr, SS, (const float2*)ssrc,
                                               (const float2*)strg, PH, S, b2,
                                               (float*)d_out, N);
}

// Round 11
// 194.825 us; speedup vs baseline: 5.4340x; 1.0021x over previous
//
#include <hip/hip_runtime.h>

#define NEG_SLOPE 0.2f
#define CBSH 7            // 128 nodes per coarse bucket
#define MAXNC 512         // max buckets (N <= 65536)

typedef __attribute__((ext_vector_type(8))) short short8;
typedef __attribute__((ext_vector_type(4))) float f32x4;

__device__ __forceinline__ unsigned short f2bf(float f) {
  unsigned u = __float_as_uint(f);
  unsigned r = (u + 0x7FFFu + ((u >> 16) & 1u)) >> 16;
  return (unsigned short)r;
}
__device__ __forceinline__ unsigned pack_bf16(float lo, float hi) {
  return (unsigned)f2bf(lo) | ((unsigned)f2bf(hi) << 16);
}
__device__ __forceinline__ float bflo(unsigned u) {
  return __uint_as_float(u << 16);
}
__device__ __forceinline__ float bfhi(unsigned u) {
  return __uint_as_float(u & 0xFFFF0000u);
}
__device__ __forceinline__ void gload_lds16(const void* g, void* l) {
  __builtin_amdgcn_global_load_lds(
      (const __attribute__((address_space(1))) unsigned*)g,
      (__attribute__((address_space(3))) unsigned*)l, 16, 0, 0);
}

// ---------------------------------------------------------------------------
// W[K][128] fp32 -> Wt[128][K] bf16 (transpose+convert).
// ---------------------------------------------------------------------------
__global__ __launch_bounds__(256) void wconv(const float* __restrict__ W,
                                             unsigned* __restrict__ Wt, int K) {
  int per = K >> 3;
  int t = blockIdx.x * 256 + threadIdx.x;
  if (t >= 128 * per) return;
  int col = t / per;
  int kc = (t - col * per) << 3;
  float w[8];
#pragma unroll
  for (int j = 0; j < 8; ++j) w[j] = W[(size_t)(kc + j) * 128 + col];
  uint4 o = make_uint4(pack_bf16(w[0], w[1]), pack_bf16(w[2], w[3]),
                       pack_bf16(w[4], w[5]), pack_bf16(w[6], w[7]));
  *(uint4*)&Wt[((size_t)col * K + kc) >> 1] = o;
}

// ---------------------------------------------------------------------------
// CSR build, bucket counting-sort (write-combining friendly).
// ---------------------------------------------------------------------------
__global__ __launch_bounds__(256) void ccount(const int* __restrict__ trg,
                                              int* __restrict__ bcnt, int E,
                                              int NC) {
  __shared__ int hist[MAXNC];
  int tid = threadIdx.x;
  for (int i = tid; i < NC; i += 256) hist[i] = 0;
  __syncthreads();
  for (int e = blockIdx.x * 256 + tid; e < E; e += gridDim.x * 256)
    atomicAdd(&hist[trg[e] >> CBSH], 1);
  __syncthreads();
  for (int i = tid; i < NC; i += 256)
    if (hist[i]) atomicAdd(&bcnt[i], hist[i]);
}

__global__ __launch_bounds__(256) void cscan(const int* __restrict__ bcnt,
                                             int* __restrict__ cbase,
                                             int* __restrict__ gcur, int NC) {
  __shared__ int s[MAXNC + 1];
  int tid = threadIdx.x;
  for (int i = tid; i < NC; i += 256) s[i] = bcnt[i];
  __syncthreads();
  if (tid == 0) {
    int run = 0;
    for (int i = 0; i < NC; ++i) {
      int v = s[i];
      s[i] = run;
      run += v;
    }
    s[NC] = run;
  }
  __syncthreads();
  for (int i = tid; i <= NC; i += 256) cbase[i] = s[i];
  for (int i = tid; i < NC; i += 256) gcur[i] = s[i];
}

__global__ __launch_bounds__(256) void cscatter(const int* __restrict__ src,
                                                const int* __restrict__ trg,
                                                int* __restrict__ gcur,
                                                unsigned* __restrict__ EB,
                                                int E, int NC) {
  __shared__ int hist[MAXNC];
  __shared__ int gb[MAXNC];
  __shared__ int lcur[MAXNC];
  __shared__ unsigned lbuf[4096];
  __shared__ unsigned short cb16[4096];
  int tid = threadIdx.x;
  int e0 = blockIdx.x * 4096;
  int cnt = E - e0;
  if (cnt > 4096) cnt = 4096;
  for (int i = tid; i < NC; i += 256) hist[i] = 0;
  __syncthreads();
  unsigned pk[16];
  unsigned short cbr[16];
  int mine = 0;
#pragma unroll
  for (int j = 0; j < 16; ++j) {
    int i = tid + j * 256;
    if (i < cnt) {
      int e = e0 + i;
      int s = src[e];
      int t = trg[e];
      int cb = t >> CBSH;
      pk[j] = ((unsigned)s << CBSH) | (unsigned)(t & ((1 << CBSH) - 1));
      cbr[j] = (unsigned short)cb;
      atomicAdd(&hist[cb], 1);
      mine = j + 1;
    }
  }
  __syncthreads();
  for (int i = tid; i < NC; i += 256)
    gb[i] = hist[i] ? atomicAdd(&gcur[i], hist[i]) : 0;
  __syncthreads();
  if (tid == 0) {
    int run = 0;
    for (int i = 0; i < NC; ++i) {
      int v = hist[i];
      hist[i] = run;
      run += v;
    }
  }
  __syncthreads();
  for (int i = tid; i < NC; i += 256) lcur[i] = hist[i];
  __syncthreads();
  for (int j = 0; j < mine; ++j) {
    int p = atomicAdd(&lcur[cbr[j]], 1);
    lbuf[p] = pk[j];
    cb16[p] = cbr[j];
  }
  __syncthreads();
  for (int i = tid; i < cnt; i += 256) {
    int cb = cb16[i];
    EB[gb[cb] + (i - hist[cb])] = lbuf[i];
  }
}

__global__ __launch_bounds__(256) void bfill(const unsigned* __restrict__ EB,
                                             const int* __restrict__ cbase,
                                             int* __restrict__ rowptr,
                                             int* __restrict__ SS, int N,
                                             int E) {
  __shared__ int deg[128], lofs[128], cur[128];
  int cb = blockIdx.x;
  int b0 = cbase[cb];
  int b1 = cbase[cb + 1];
  int n0 = cb << CBSH;
  int tid = threadIdx.x;
  if (tid < 128) deg[tid] = 0;
  __syncthreads();
  for (int i = b0 + tid; i < b1; i += 256)
    atomicAdd(&deg[EB[i] & ((1 << CBSH) - 1)], 1);
  __syncthreads();
  if (tid == 0) {
    int run = b0;
    for (int l = 0; l < 128; ++l) {
      lofs[l] = run;
      run += deg[l];
    }
  }
  __syncthreads();
  if (tid < 128) {
    cur[tid] = lofs[tid];
    int n = n0 + tid;
    if (n < N) rowptr[n] = lofs[tid];
  }
  if (cb == 0 && tid == 0) rowptr[N] = E;
  __syncthreads();
  for (int i = b0 + tid; i < b1; i += 256) {
    unsigned pk = EB[i];
    int pos = atomicAdd(&cur[pk & ((1 << CBSH) - 1)], 1);
    SS[pos] = (int)(pk >> CBSH);
  }
}

// ---------------------------------------------------------------------------
// Fused dual bf16-MFMA GEMM — EXACT round-8-input structure (verified
// passing): 2-phase pipelined, fragment-ordered LDS, gload_lds B staging,
// per-K-step barrier. Only deltas: (i) AF32 template selects fp32 A
// (reg-stage+pack) vs packed-bf16 A rows (uint4 load, same mapping);
// (ii) skip output stored as packed bf16 (Cb) instead of fp32.
// LDS per buf (20480 B): A @0 (4KB), BP @4096, BS @12288; 2 bufs; Cs alias.
// mfma 16x16x32_bf16: A row=lane&15,k=(lane>>4)*8+i; B col=lane&15;
// D col=lane&15,row=(lane>>4)*4+reg.
// ---------------------------------------------------------------------------
template <int KK, bool AF32>
__global__ __launch_bounds__(256) void gemm_dual(
    const void* __restrict__ Av, const unsigned* __restrict__ BtP,
    const unsigned* __restrict__ BtS, unsigned* __restrict__ Cb,
    unsigned* __restrict__ PH, const float* __restrict__ a_src,
    const float* __restrict__ a_trg, float* __restrict__ ssrc,
    float* __restrict__ strg, int M) {
  __shared__ __align__(16) char ldsraw[40960];
  float(*Cs)[132] = (float(*)[132])ldsraw;

  const int tid = threadIdx.x;
  const int lane = tid & 63;
  const int w = tid >> 6;
  const int row0 = blockIdx.x * 64;

  f32x4 accP[8], accS[8];
#pragma unroll
  for (int c = 0; c < 8; ++c) {
    accP[c] = (f32x4)0.f;
    accS[c] = (f32x4)0.f;
  }

  // A staging map (identical to round-8-input): row arow=tid>>2, k-quarter
  // akq=(tid&3)*8; fragment-ordered chunk slot abyte.
  const int arow = tid >> 2;
  const int akq = (tid & 3) << 3;
  const int agr = row0 + arow;
  const int abyte =
      ((((arow >> 4) << 6) | ((tid & 3) << 4) | (arow & 15)) << 4);
  const unsigned short* BP16 = (const unsigned short*)BtP;
  const unsigned short* BS16 = (const unsigned short*)BtS;
  const int bg = lane >> 4;
  const int br = lane & 15;

  const int nt = KK >> 5;

  auto stage_b = [&](int buf, int k0) {
    char* sb = ldsraw + buf * 20480;
#pragma unroll
    for (int i = 0; i < 2; ++i) {
      int c = w * 2 + i;
      size_t eoff = (size_t)(16 * c + br) * KK + k0 + 8 * bg;
      gload_lds16(BP16 + eoff, sb + 4096 + c * 1024);
      gload_lds16(BS16 + eoff, sb + 12288 + c * 1024);
    }
  };
  auto load_a = [&](int k0, uint4& p) {
    if constexpr (AF32) {
      const float* A = (const float*)Av;
      float4 v0 = make_float4(0.f, 0.f, 0.f, 0.f), v1 = v0;
      if (agr < M) {
        v0 = *(const float4*)&A[(size_t)agr * KK + k0 + akq];
        v1 = *(const float4*)&A[(size_t)agr * KK + k0 + akq + 4];
      }
      p = make_uint4(pack_bf16(v0.x, v0.y), pack_bf16(v0.z, v0.w),
                     pack_bf16(v1.x, v1.y), pack_bf16(v1.z, v1.w));
    } else {
      const unsigned short* A = (const unsigned short*)Av;
      p = make_uint4(0u, 0u, 0u, 0u);
      if (agr < M) p = *(const uint4*)&A[(size_t)agr * KK + k0 + akq];
    }
  };
  auto write_a = [&](int buf, const uint4& p) {
    *(uint4*)(ldsraw + buf * 20480 + abyte) = p;
  };

  {
    uint4 p;
    stage_b(0, 0);
    load_a(0, p);
    write_a(0, p);
  }
  __syncthreads();

  int cur = 0;
  for (int t = 0; t < nt; ++t) {
    uint4 p;
    const bool pf = (t + 1 < nt);
    if (pf) {
      stage_b(cur ^ 1, (t + 1) << 5);
      load_a((t + 1) << 5, p);
    }
    const char* sb = ldsraw + cur * 20480;
    short8 af = *(const short8*)(sb + w * 1024 + lane * 16);
#pragma unroll
    for (int c = 0; c < 8; ++c) {
      short8 bp = *(const short8*)(sb + 4096 + c * 1024 + lane * 16);
      accP[c] =
          __builtin_amdgcn_mfma_f32_16x16x32_bf16(af, bp, accP[c], 0, 0, 0);
      short8 bs = *(const short8*)(sb + 12288 + c * 1024 + lane * 16);
      accS[c] =
          __builtin_amdgcn_mfma_f32_16x16x32_bf16(af, bs, accS[c], 0, 0, 0);
    }
    if (pf) write_a(cur ^ 1, p);
    __syncthreads();
    cur ^= 1;
  }

  const int hrow = lane >> 5;
  const int c32 = lane & 31;

  // ---- proj epilogue: PH (bf16) + fused scores ----
#pragma unroll
  for (int c = 0; c < 8; ++c)
#pragma unroll
    for (int r = 0; r < 4; ++r)
      Cs[16 * w + ((lane >> 4) << 2) + r][16 * c + (lane & 15)] = accP[c][r];
  __syncthreads();
#pragma unroll
  for (int i = 0; i < 8; ++i) {
    int lr = 16 * w + 2 * i + hrow;
    int gr = row0 + lr;
    if (gr < M) {
      float4 v = *(const float4*)&Cs[lr][c32 * 4];
      *(uint2*)&PH[(size_t)gr * 64 + c32 * 2] =
          make_uint2(pack_bf16(v.x, v.y), pack_bf16(v.z, v.w));
    }
  }
  {
    int srow = tid >> 2;
    int q = tid & 3;
    int gr = row0 + srow;
    float ds = 0.f, dt = 0.f;
#pragma unroll
    for (int j = 0; j < 8; ++j) {
      int col = q * 32 + j * 4;
      float4 v = *(const float4*)&Cs[srow][col];
      float4 asv = *(const float4*)&a_src[col];
      float4 atv = *(const float4*)&a_trg[col];
      ds += v.x * asv.x + v.y * asv.y + v.z * asv.z + v.w * asv.w;
      dt += v.x * atv.x + v.y * atv.y + v.z * atv.z + v.w * atv.w;
    }
    ds += __shfl_xor(ds, 1, 64);
    dt += __shfl_xor(dt, 1, 64);
    if (gr < M && (q & 1) == 0) {
      int h = q >> 1;
      ssrc[gr * 2 + h] = ds;
      strg[gr * 2 + h] = dt;
    }
  }
  __syncthreads();

  // ---- skip epilogue: Cb (packed bf16) ----
#pragma unroll
  for (int c = 0; c < 8; ++c)
#pragma unroll
    for (int r = 0; r < 4; ++r)
      Cs[16 * w + ((lane >> 4) << 2) + r][16 * c + (lane & 15)] = accS[c][r];
  __syncthreads();
#pragma unroll
  for (int i = 0; i < 8; ++i) {
    int lr = 16 * w + 2 * i + hrow;
    int gr = row0 + lr;
    if (gr < M) {
      float4 v = *(const float4*)&Cs[lr][c32 * 4];
      *(uint2*)&Cb[(size_t)gr * 64 + c32 * 2] =
          make_uint2(pack_bf16(v.x, v.y), pack_bf16(v.z, v.w));
    }
  }
}

// ---------------------------------------------------------------------------
// Fused aggregation: one wave per node; weights recomputed on the fly; bf16
// messages from PH; bf16 skip from Sb; readlane-broadcast indices; 4 edges in
// flight. LAYER==1: out = packed-bf16 relu(agg+skip+b) -> (N,64 uints).
// LAYER==2: out = fp32 head-mean (N,64).
// ---------------------------------------------------------------------------
template <int LAYER>
__global__ __launch_bounds__(256) void aggregate(
    const int* __restrict__ rowptr, const int* __restrict__ SS,
    const float2* __restrict__ ssrc, const float2* __restrict__ strg,
    const unsigned* __restrict__ PH, const unsigned* __restrict__ Sb,
    const float* __restrict__ bias, void* __restrict__ Outv, int Nn) {
  int wid = (int)((blockIdx.x * blockDim.x + threadIdx.x) >> 6);
  int lane = threadIdx.x & 63;
  if (wid >= Nn) return;
  int n = wid;
  bool hi = lane >= 32;
  float2 st = strg[n];
  float et = hi ? st.y : st.x;
  int beg = rowptr[n];
  int end = rowptr[n + 1];
  float accx = 0.f, accy = 0.f, dsum = 0.f;

  for (int base = beg; base < end; base += 64) {
    int cnt = end - base;
    if (cnt > 64) cnt = 64;
    int idx = base + lane;
    int sv = (idx < end) ? SS[idx] : 0;
    int j = 0;
    for (; j + 4 <= cnt; j += 4) {
      int s0 = __builtin_amdgcn_readlane(sv, j + 0);
      int s1 = __builtin_amdgcn_readlane(sv, j + 1);
      int s2 = __builtin_amdgcn_readlane(sv, j + 2);
      int s3 = __builtin_amdgcn_readlane(sv, j + 3);
      unsigned w0 = PH[(size_t)s0 * 64 + lane];
      unsigned w1 = PH[(size_t)s1 * 64 + lane];
      unsigned w2 = PH[(size_t)s2 * 64 + lane];
      unsigned w3 = PH[(size_t)s3 * 64 + lane];
      float2 e0 = ssrc[s0];
      float2 e1 = ssrc[s1];
      float2 e2 = ssrc[s2];
      float2 e3 = ssrc[s3];
      float z0 = (hi ? e0.y : e0.x) + et;
      float z1 = (hi ? e1.y : e1.x) + et;
      float z2 = (hi ? e2.y : e2.x) + et;
      float z3 = (hi ? e3.y : e3.x) + et;
      z0 = (z0 >= 0.f) ? z0 : NEG_SLOPE * z0;
      z1 = (z1 >= 0.f) ? z1 : NEG_SLOPE * z1;
      z2 = (z2 >= 0.f) ? z2 : NEG_SLOPE * z2;
      z3 = (z3 >= 0.f) ? z3 : NEG_SLOPE * z3;
      float g0 = __expf(z0), g1 = __expf(z1), g2 = __expf(z2), g3 = __expf(z3);
      dsum += (g0 + g1) + (g2 + g3);
      accx = fmaf(bflo(w0), g0, accx);
      accy = fmaf(bfhi(w0), g0, accy);
      accx = fmaf(bflo(w1), g1, accx);
      accy = fmaf(bfhi(w1), g1, accy);
      accx = fmaf(bflo(w2), g2, accx);
      accy = fmaf(bfhi(w2), g2, accy);
      accx = fmaf(bflo(w3), g3, accx);
      accy = fmaf(bfhi(w3), g3, accy);
    }
    for (; j < cnt; ++j) {
      int s0 = __builtin_amdgcn_readlane(sv, j);
      unsigned w0 = PH[(size_t)s0 * 64 + lane];
      float2 e0 = ssrc[s0];
      float z0 = (hi ? e0.y : e0.x) + et;
      z0 = (z0 >= 0.f) ? z0 : NEG_SLOPE * z0;
      float g0 = __expf(z0);
      dsum += g0;
      accx = fmaf(bflo(w0), g0, accx);
      accy = fmaf(bfhi(w0), g0, accy);
    }
  }

  float inv = 1.0f / (dsum + 1e-16f);
  accx *= inv;
  accy *= inv;
  unsigned skv = Sb[(size_t)n * 64 + lane];
  float skx = bflo(skv);
  float sky = bfhi(skv);
  if (LAYER == 1) {
    float2 b = *(const float2*)&bias[lane * 2];
    float zx = fmaxf(accx + skx + b.x, 0.f);
    float zy = fmaxf(accy + sky + b.y, 0.f);
    ((unsigned*)Outv)[(size_t)n * 64 + lane] = pack_bf16(zx, zy);
  } else {
    float zx = accx + skx;
    float zy = accy + sky;
    float ox = __shfl(zx, lane + 32, 64);
    float oy = __shfl(zy, lane + 32, 64);
    if (lane < 32) {
      float2 b = *(const float2*)&bias[lane * 2];
      float rx = 0.5f * (zx + ox) + b.x;
      float ry = 0.5f * (zy + oy) + b.y;
      *(float2*)&((float*)Outv)[(size_t)n * 64 + lane * 2] =
          make_float2(rx, ry);
    }
  }
}

// ---------------------------------------------------------------------------
extern "C" void kernel_launch(void* const* d_in, const int* in_sizes, int n_in,
                              void* d_out, int out_size, void* d_ws,
                              size_t ws_size, hipStream_t stream) {
  const float* x = (const float*)d_in[0];
  const int* ei = (const int*)d_in[1];
  const float* W0 = (const float*)d_in[2];
  const float* a_src0 = (const float*)d_in[3];
  const float* a_trg0 = (const float*)d_in[4];
  const float* Wsk0 = (const float*)d_in[5];
  const float* b0 = (const float*)d_in[6];
  const float* W2 = (const float*)d_in[7];
  const float* a_src2 = (const float*)d_in[8];
  const float* a_trg2 = (const float*)d_in[9];
  const float* Wsk2 = (const float*)d_in[10];
  const float* b2 = (const float*)d_in[11];

  const int FIN = 256;
  const int N = in_sizes[0] / FIN;
  const int E = in_sizes[1] / 2;
  const int* src = ei;
  const int* trg = ei + E;
  const int NC = (N + (1 << CBSH) - 1) >> CBSH;

  char* base = (char*)d_ws;
  size_t off = 0;
  auto alloc = [&](size_t bytes) -> void* {
    void* p = base + off;
    off += (bytes + 255) & ~(size_t)255;
    return p;
  };
  unsigned* PH = (unsigned*)alloc((size_t)N * 64 * sizeof(unsigned));
  unsigned* Sb = (unsigned*)alloc((size_t)N * 64 * sizeof(unsigned));
  unsigned* Hb = (unsigned*)alloc((size_t)N * 64 * sizeof(unsigned));
  int* SS = (int*)alloc((size_t)E * sizeof(int));
  unsigned* EB = (unsigned*)alloc((size_t)E * sizeof(unsigned));
  float* ssrc = (float*)alloc((size_t)N * 2 * sizeof(float));
  float* strg = (float*)alloc((size_t)N * 2 * sizeof(float));
  int* rowptr = (int*)alloc((size_t)(N + 1) * sizeof(int));
  int* bcnt = (int*)alloc((size_t)MAXNC * sizeof(int));
  int* cbase = (int*)alloc((size_t)(MAXNC + 1) * sizeof(int));
  int* gcur = (int*)alloc((size_t)MAXNC * sizeof(int));
  unsigned* WtP0 = (unsigned*)alloc((size_t)128 * 256 * 2);
  unsigned* WtS0 = (unsigned*)alloc((size_t)128 * 256 * 2);
  unsigned* WtP2 = (unsigned*)alloc((size_t)128 * 128 * 2);
  unsigned* WtS2 = (unsigned*)alloc((size_t)128 * 128 * 2);

  hipMemsetAsync(bcnt, 0, (size_t)MAXNC * sizeof(int), stream);

  dim3 blk(256);
  int gemmBlocks = (N + 63) / 64;
  int nodeBlocks = (N + 3) / 4;
  int chunkBlocks = (E + 4095) / 4096;

  // ---- weight prep ----
  wconv<<<16, blk, 0, stream>>>(W0, WtP0, 256);
  wconv<<<16, blk, 0, stream>>>(Wsk0, WtS0, 256);
  wconv<<<8, blk, 0, stream>>>(W2, WtP2, 128);
  wconv<<<8, blk, 0, stream>>>(Wsk2, WtS2, 128);

  // ---- CSR build (bucket counting sort) ----
  ccount<<<256, blk, 0, stream>>>(trg, bcnt, E, NC);
  cscan<<<1, blk, 0, stream>>>(bcnt, cbase, gcur, NC);
  cscatter<<<chunkBlocks, blk, 0, stream>>>(src, trg, gcur, EB, E, NC);
  bfill<<<NC, blk, 0, stream>>>(EB, cbase, rowptr, SS, N, E);

  // ---- layer 1 ----
  gemm_dual<256, true><<<gemmBlocks, blk, 0, stream>>>(
      x, WtP0, WtS0, Sb, PH, a_src0, a_trg0, ssrc, strg, N);
  aggregate<1><<<nodeBlocks, blk, 0, stream>>>(rowptr, SS, (const float2*)ssrc,
                                               (const float2*)strg, PH, Sb, b0,
                                               Hb, N);
  // ---- layer 2 (h lives in Hb, bf16) ----
  gemm_dual<128, false><<<gemmBlocks, blk, 0, stream>>>(
      Hb, WtP2, WtS2, Sb, PH, a_src2, a_trg2, ssrc, strg, N);
  aggregate<2><<<nodeBlocks, blk, 0, stream>>>(rowptr, SS, (const float2*)ssrc,
                                               (const float2*)strg, PH, Sb, b2,
                                               d_out, N);
}